// Round 5
// baseline (232.390 us; speedup 1.0000x reference)
//
#include <hip/hip_runtime.h>
#include <hip/hip_bf16.h>

// Problem constants (from reference setup_inputs)
#define BB    4
#define NTOT  16384
#define CC    256
#define HH    8
#define DD    64
#define HD    512
#define OUTC  256

typedef unsigned short u16;
typedef unsigned int u32;
typedef __attribute__((ext_vector_type(8))) short bf16x8;   // 8 bf16 in 4 VGPRs
typedef __attribute__((ext_vector_type(4))) float f32x4;
typedef __attribute__((ext_vector_type(4))) short u16x4;
typedef __attribute__((ext_vector_type(4))) u32 u32x4;

__device__ __forceinline__ float b2f(u16 u) {
    union { float f; u32 i; } x; x.i = ((u32)u) << 16; return x.f;
}
__device__ __forceinline__ u16 f2b(float f) {
    union { float f; u32 i; } x; x.f = f;
    u32 r = x.i + 0x7fffu + ((x.i >> 16) & 1u);   // round-to-nearest-even
    return (u16)(r >> 16);
}

#define GLD(gp, lp) __builtin_amdgcn_global_load_lds( \
    (const __attribute__((address_space(1))) void*)(gp), \
    (__attribute__((address_space(3))) void*)(lp), 16, 0, 0)

#define MFMA(a, b, c) __builtin_amdgcn_mfma_f32_16x16x32_bf16((a), (b), (c), 0, 0, 0)

// ---------------------------------------------------------------------------
// wcvt: 4 weight matrices (each 131072 f32) -> bf16. grid (64, 1, 4).
// ---------------------------------------------------------------------------
__global__ __launch_bounds__(256) void wcvt(
    const float* __restrict__ Wq, const float* __restrict__ Wk,
    const float* __restrict__ Wv, const float* __restrict__ Wo,
    u16* __restrict__ q, u16* __restrict__ k,
    u16* __restrict__ v, u16* __restrict__ o)
{
    const int z = blockIdx.z;
    const float* src = z == 0 ? Wq : z == 1 ? Wk : z == 2 ? Wv : Wo;
    u16* dst = z == 0 ? q : z == 1 ? k : z == 2 ? v : o;
    const int i = (blockIdx.x * 256 + threadIdx.x) * 8;
    const float4 a = *(const float4*)(src + i);
    const float4 b = *(const float4*)(src + i + 4);
    union { bf16x8 v; u16 s[8]; } w;
    w.s[0] = f2b(a.x); w.s[1] = f2b(a.y); w.s[2] = f2b(a.z); w.s[3] = f2b(a.w);
    w.s[4] = f2b(b.x); w.s[5] = f2b(b.y); w.s[6] = f2b(b.z); w.s[7] = f2b(b.w);
    *(bf16x8*)(dst + i) = w.v;
}

// ---------------------------------------------------------------------------
// ggemm v6: occupancy split. Gp[chunk][i][j] = sum_{n in chunk} u_b[n][i]*u_b[n][j].
// 256-thr blocks, grid 512 = 2 halves x (4 b x 64 ck); block computes a
// 128x256 half of the G-tile (half = z>>8 so the two halves of a chunk are
// 256 apart -> same XCD -> shared-u L2 locality). 2 blocks/CU co-resident
// (was 1 with 512 thr) -> barrier stalls of one block overlap the other's
// compute. Staging structure = proven v4 (single Ts, 2 barriers/iter,
// 9-stride scatter, prefetch between barriers). Each thread stages TWO
// n-pairs (sp0, sp0+8). Only half-0 blocks emit u_b + suP (once each).
// ---------------------------------------------------------------------------
__global__ __launch_bounds__(256) void ggemm(
    const float* __restrict__ u, float* __restrict__ Gp, float* __restrict__ suP,
    u16* __restrict__ u_b)
{
    __shared__ u32 Ts[16 * 290];   // 18.6 KB
    const int z = blockIdx.x;
    const int half = z >> 8;        // output-row half (0/1)
    const int cg = z & 255;         // global chunk 0..255
    const int b = cg >> 6, ck = cg & 63;
    const float* base = u + (long long)b * NTOT * CC + (long long)ck * 256 * CC;
    u16* ub_base = u_b + (long long)b * NTOT * CC + (long long)ck * 256 * CC;
    const int t = threadIdx.x, w = t >> 6, l = t & 63;
    const int wy = w >> 1, wx = w & 1;   // 2x2 wave grid over 128x256
    const int r16 = l & 15, quad = l >> 4;
    const int sp0 = t >> 5;          // first n-pair 0..7 (second = sp0+8)
    const int sq = t & 31;           // c-octet 0..31

    // fragment column-swizzle bases: col c -> 9*(c>>3) + (c&7), +18 per 16 cols
    const int csa0 = 9 * ((half * 128 + wy * 64 + r16) >> 3) + (r16 & 7);  // + 18*i
    const int csb0 = 9 * ((wx * 128 + r16) >> 3) + (r16 & 7);              // + 18*j
    const int pr0 = 4 * quad * 290;

    f32x4 acc[4][8] = {};
    float su8[8] = {};

    float4 a0, a1, b0, b1, c0, c1, d0, d1;
    {
        const float* s1 = base + (long long)(2 * sp0) * CC + sq * 8;
        const float* s2 = base + (long long)(2 * sp0 + 16) * CC + sq * 8;
        a0 = *(const float4*)s1;        a1 = *(const float4*)(s1 + 4);
        b0 = *(const float4*)(s1 + CC); b1 = *(const float4*)(s1 + CC + 4);
        c0 = *(const float4*)s2;        c1 = *(const float4*)(s2 + 4);
        d0 = *(const float4*)(s2 + CC); d1 = *(const float4*)(s2 + CC + 4);
    }

    for (int it = 0; it < 8; it++) {
        __syncthreads();   // prev iter's LDS frag reads complete (no-op first)
        {   // cvt + pair-pack + 9-stride scatter (conflict-free, proven v3)
            union { bf16x8 v; u16 q[8]; } ra, rb, rc, rd;
            ra.q[0] = f2b(a0.x); ra.q[1] = f2b(a0.y); ra.q[2] = f2b(a0.z); ra.q[3] = f2b(a0.w);
            ra.q[4] = f2b(a1.x); ra.q[5] = f2b(a1.y); ra.q[6] = f2b(a1.z); ra.q[7] = f2b(a1.w);
            rb.q[0] = f2b(b0.x); rb.q[1] = f2b(b0.y); rb.q[2] = f2b(b0.z); rb.q[3] = f2b(b0.w);
            rb.q[4] = f2b(b1.x); rb.q[5] = f2b(b1.y); rb.q[6] = f2b(b1.z); rb.q[7] = f2b(b1.w);
            rc.q[0] = f2b(c0.x); rc.q[1] = f2b(c0.y); rc.q[2] = f2b(c0.z); rc.q[3] = f2b(c0.w);
            rc.q[4] = f2b(c1.x); rc.q[5] = f2b(c1.y); rc.q[6] = f2b(c1.z); rc.q[7] = f2b(c1.w);
            rd.q[0] = f2b(d0.x); rd.q[1] = f2b(d0.y); rd.q[2] = f2b(d0.z); rd.q[3] = f2b(d0.w);
            rd.q[4] = f2b(d1.x); rd.q[5] = f2b(d1.y); rd.q[6] = f2b(d1.z); rd.q[7] = f2b(d1.w);
            u32* dst1 = Ts + sp0 * 290 + 9 * sq;
            u32* dst2 = Ts + (sp0 + 8) * 290 + 9 * sq;
#pragma unroll
            for (int k = 0; k < 8; k++) {
                dst1[k] = (u32)ra.q[k] | ((u32)rb.q[k] << 16);
                dst2[k] = (u32)rc.q[k] | ((u32)rd.q[k] << 16);
            }
            if (half == 0) {
#pragma unroll
                for (int k = 0; k < 8; k++)
                    su8[k] += (b2f(ra.q[k]) + b2f(rb.q[k])) + (b2f(rc.q[k]) + b2f(rd.q[k]));
                u16* ub = ub_base + (long long)(it * 32 + 2 * sp0) * CC + sq * 8;
                *(bf16x8*)ub = ra.v;
                *(bf16x8*)(ub + CC) = rb.v;
                *(bf16x8*)(ub + 16 * CC) = rc.v;
                *(bf16x8*)(ub + 17 * CC) = rd.v;
            }
        }
        if (it < 7) {   // prefetch next 32-n slab (overlaps barrier+compute)
            const float* s1 = base + (long long)((it + 1) * 32 + 2 * sp0) * CC + sq * 8;
            const float* s2 = s1 + 16 * CC;
            a0 = *(const float4*)s1;        a1 = *(const float4*)(s1 + 4);
            b0 = *(const float4*)(s1 + CC); b1 = *(const float4*)(s1 + CC + 4);
            c0 = *(const float4*)s2;        c1 = *(const float4*)(s2 + 4);
            d0 = *(const float4*)(s2 + CC); d1 = *(const float4*)(s2 + CC + 4);
        }
        __syncthreads();

        bf16x8 a[4], bb[8];
#pragma unroll
        for (int i = 0; i < 4; i++) {
            const int cs = pr0 + csa0 + 18 * i;
            union { u32x4 u4; bf16x8 h; } f;
            f.u4[0] = Ts[cs];       f.u4[1] = Ts[290 + cs];
            f.u4[2] = Ts[580 + cs]; f.u4[3] = Ts[870 + cs];
            a[i] = f.h;
        }
#pragma unroll
        for (int j = 0; j < 8; j++) {
            const int cs = pr0 + csb0 + 18 * j;
            union { u32x4 u4; bf16x8 h; } f;
            f.u4[0] = Ts[cs];       f.u4[1] = Ts[290 + cs];
            f.u4[2] = Ts[580 + cs]; f.u4[3] = Ts[870 + cs];
            bb[j] = f.h;
        }
#pragma unroll
        for (int i = 0; i < 4; i++)
#pragma unroll
            for (int j = 0; j < 8; j++)
                acc[i][j] = MFMA(a[i], bb[j], acc[i][j]);
    }

    float* Cp = Gp + (long long)cg * 65536;
#pragma unroll
    for (int i = 0; i < 4; i++)
#pragma unroll
        for (int j = 0; j < 8; j++)
#pragma unroll
            for (int rr = 0; rr < 4; rr++)
                Cp[(half * 128 + wy * 64 + 16 * i + quad * 4 + rr) * 256
                   + wx * 128 + 16 * j + r16] = acc[i][j][rr];

    if (half == 0) {
        // su reduce via Ts scratch: [8][264] f32 = 8.4 KB
        __syncthreads();
        float* S = (float*)Ts;
#pragma unroll
        for (int k = 0; k < 8; k++) S[sp0 * 264 + sq * 8 + k] = su8[k];
        __syncthreads();
        float s = 0.f;
#pragma unroll
        for (int p = 0; p < 8; p++) s += S[p * 264 + t];
        suP[cg * 256 + t] = s;
    }
}

// ---------------------------------------------------------------------------
// gred: Gb[b][i][j] = bf16(sum_{ck<64} Gp), f32x4 per thread (4 cols).
// grid (64, 4), 256 thr; block x==0 also reduces suP -> su.
// ---------------------------------------------------------------------------
__global__ __launch_bounds__(256) void gred(
    const float* __restrict__ Gp, const float* __restrict__ suP,
    u16* __restrict__ Gb, float* __restrict__ su)
{
    const int b = blockIdx.y, t = threadIdx.x;
    const int row = blockIdx.x * 4 + (t >> 6);
    const int col = (t & 63) * 4;
    const float* p = Gp + (long long)(b * 64) * 65536 + row * 256 + col;
    f32x4 s = {};
#pragma unroll
    for (int ck = 0; ck < 64; ck++) {
        f32x4 v = *(const f32x4*)(p + (long long)ck * 65536);
        s[0] += v[0]; s[1] += v[1]; s[2] += v[2]; s[3] += v[3];
    }
    union { u16x4 v; u16 q[4]; } pk;
#pragma unroll
    for (int k = 0; k < 4; k++) pk.q[k] = f2b(s[k]);
    *(u16x4*)(Gb + (long long)b * 65536 + row * 256 + col) = pk.v;

    if (blockIdx.x == 0) {
        float s2 = 0.f;
#pragma unroll
        for (int ck = 0; ck < 64; ck++) s2 += suP[(b * 64 + ck) * 256 + t];
        su[b * 256 + t] = s2;
    }
}

// ---------------------------------------------------------------------------
// skvz: serial tail per (b,h). Inputs: P2 = [Wk;Wv]_stacked x G (bf16), su.
// stats via direct row-dots; S = Pk Wv^T (frags from global); kv -> kvT LDS;
// WqT staging + Y-phase. grid (32), 256 thr.
// ---------------------------------------------------------------------------
__global__ __launch_bounds__(256) void skvz(
    const u16* __restrict__ P2, const float* __restrict__ su,
    const u16* __restrict__ Wk_b, const u16* __restrict__ Wv_b,
    const u16* __restrict__ Wq_b, u16* __restrict__ Zt)
{
    __shared__ u16 pool[20480];   // kvTL 8KB + WqTL 32KB
    __shared__ float mkL[64], rkL[64], mvL[64], rvL[64];

    const int bx = blockIdx.x, b = bx >> 3, h = bx & 7;
    const int t = threadIdx.x, w = t >> 6, l = t & 63;
    const int r16 = l & 15, quad = l >> 4;

    const u16* WkH = Wk_b + (h * 64) * 256;
    const u16* WvH = Wv_b + (h * 64) * 256;
    const u16* PkH = P2 + (long long)b * 262144 + (h * 64) * 256;
    const u16* PvH = P2 + (long long)b * 262144 + (512 + h * 64) * 256;

    // ---- stats: 2 threads per row (128 rows: 64 k + 64 v) ----
    {
        const int row = t >> 1, half = t & 1;
        const u16* Prow = (row < 64 ? PkH + row * 256 : PvH + (row - 64) * 256) + half * 128;
        const u16* Wrow = (row < 64 ? WkH + row * 256 : WvH + (row - 64) * 256) + half * 128;
        const float* suB = su + b * 256 + half * 128;
        float e2 = 0.f, m = 0.f;
#pragma unroll
        for (int c8 = 0; c8 < 16; c8++) {
            bf16x8 pw = *(const bf16x8*)(Prow + c8 * 8);
            bf16x8 ww = *(const bf16x8*)(Wrow + c8 * 8);
#pragma unroll
            for (int k = 0; k < 8; k++) {
                const float wv_ = b2f((u16)ww[k]);
                e2 += b2f((u16)pw[k]) * wv_;
                m  += wv_ * suB[c8 * 8 + k];
            }
        }
        e2 += __shfl_xor(e2, 1);
        m  += __shfl_xor(m, 1);
        if (half == 0) {
            m *= (1.0f / NTOT);
            const float r = rsqrtf(e2 * (1.0f / NTOT) - m * m + 1e-5f);
            if (row < 64) { mkL[row] = m; rkL[row] = r; }
            else          { mvL[row - 64] = m; rvL[row - 64] = r; }
        }
    }
    __syncthreads();

    // ---- S-phase: S[d,e] = sum_c Pk[d,c] Wv[e,c]; frags from global ----
    const int mh = (w >> 1) * 32, nh = (w & 1) * 32;
    float mkR[2][4], rkR[2][4], mvR[2], rvR[2];
#pragma unroll
    for (int i = 0; i < 2; i++)
#pragma unroll
        for (int rr = 0; rr < 4; rr++) {
            mkR[i][rr] = mkL[mh + 16 * i + quad * 4 + rr];
            rkR[i][rr] = rkL[mh + 16 * i + quad * 4 + rr];
        }
#pragma unroll
    for (int j = 0; j < 2; j++) {
        mvR[j] = mvL[nh + 16 * j + r16];
        rvR[j] = rvL[nh + 16 * j + r16];
    }

    f32x4 accs[2][2] = {};
    for (int ch = 0; ch < 8; ch++) {
        const int ko = quad * 8;
        bf16x8 ap[2], bv[2];
#pragma unroll
        for (int i = 0; i < 2; i++)
            ap[i] = *(const bf16x8*)(PkH + (mh + 16 * i + r16) * 256 + ch * 32 + ko);
#pragma unroll
        for (int j = 0; j < 2; j++)
            bv[j] = *(const bf16x8*)(WvH + (nh + 16 * j + r16) * 256 + ch * 32 + ko);
#pragma unroll
        for (int i = 0; i < 2; i++)
#pragma unroll
            for (int j = 0; j < 2; j++)
                accs[i][j] = MFMA(ap[i], bv[j], accs[i][j]);
    }

    // ---- kv -> kvTL; WqTL ----
    u16* kvTL = pool;            // 8 KB
    u16* WqTL = pool + 4096;     // 32 KB
#pragma unroll
    for (int i = 0; i < 2; i++)
#pragma unroll
        for (int j = 0; j < 2; j++)
#pragma unroll
            for (int rr = 0; rr < 4; rr++) {
                const int d = mh + 16 * i + quad * 4 + rr;
                const int e = nh + 16 * j + r16;
                const float kv = rkR[i][rr] * rvR[j] *
                    (accs[i][j][rr] * (1.0f / NTOT) - mkR[i][rr] * mvR[j]);
                kvTL[(d >> 5) * 2048 + e * 32 + (d & 31)] = f2b(kv);
            }
    {
        const int d = t >> 2, q = t & 3;
        const u16* Wrow = Wq_b + (h * 64 + d) * 256 + q * 64;
#pragma unroll
        for (int s = 0; s < 8; s++) {
            bf16x8 raw = *(const bf16x8*)(Wrow + s * 8);
#pragma unroll
            for (int k = 0; k < 8; k++) {
                const int c = q * 64 + s * 8 + k;
                WqTL[(d >> 5) * 8192 + c * 32 + (d & 31)] = (u16)raw[k];
            }
        }
    }
    __syncthreads();

    // ---- Y-phase ----
    f32x4 accy[4][4] = {};
#pragma unroll
    for (int ch = 0; ch < 2; ch++) {
        const int ko = quad * 8;
        bf16x8 akv[4], bq[4];
#pragma unroll
        for (int i = 0; i < 4; i++)
            akv[i] = *(const bf16x8*)(kvTL + ch * 2048 + (16 * i + r16) * 32 + ko);
#pragma unroll
        for (int j = 0; j < 4; j++)
            bq[j] = *(const bf16x8*)(WqTL + ch * 8192 + (w * 64 + 16 * j + r16) * 32 + ko);
#pragma unroll
        for (int i = 0; i < 4; i++)
#pragma unroll
            for (int j = 0; j < 4; j++)
                accy[i][j] = MFMA(akv[i], bq[j], accy[i][j]);
    }
#pragma unroll
    for (int i = 0; i < 4; i++)
#pragma unroll
        for (int j = 0; j < 4; j++) {
            const int c = w * 64 + 16 * j + r16;
            const int e0 = 16 * i + quad * 4;
            union { u16x4 v; u16 s[4]; } pk;
#pragma unroll
            for (int rr = 0; rr < 4; rr++) pk.s[rr] = f2b(accy[i][j][rr]);
            *(u16x4*)(Zt + ((long long)(b * 256 + c)) * 512 + h * 64 + e0) = pk.v;
        }
}

// ---------------------------------------------------------------------------
// gemm_bt v2 (2-phase dbuf): C[m,n] = sum_k A[m,k]*Bm[n,k] (+bias[n]).
// ---------------------------------------------------------------------------
template <typename CT>
__global__ __launch_bounds__(256) void gemm_bt(
    const u16* __restrict__ A, const u16* __restrict__ Bm,
    CT* __restrict__ C, const float* __restrict__ bias,
    int K, int lda, int ldc,
    long long aStride, long long bStride, long long cStride)
{
    __shared__ u16 As[2][128 * 32];
    __shared__ u16 Bs[2][128 * 32];

    const int bz = blockIdx.z;
    A  += (long long)bz * aStride;
    Bm += (long long)bz * bStride;
    C  += (long long)bz * cStride;

    const int m0 = blockIdx.x * 128;
    const int n0 = blockIdx.y * 128;
    const int t  = threadIdx.x;
    const int wv = t >> 6, l = t & 63;
    const int wy = wv >> 1, wx = wv & 1;
    const int r16  = l & 15;
    const int quad = l >> 4;
    const int srow = wv * 16 + (l >> 2);
    const int scol = (l & 3) * 8;

    auto stage = [&](int kk, int buf) {
#pragma unroll
        for (int s = 0; s < 2; s++) {
            GLD(A + (long long)(m0 + s * 64 + srow) * lda + kk + scol,
                As[buf] + s * 2048 + wv * 512);
            GLD(Bm + (long long)(n0 + s * 64 + srow) * K + kk + scol,
                Bs[buf] + s * 2048 + wv * 512);
        }
    };

    f32x4 acc[4][4] = {};

    stage(0, 0);
    __syncthreads();
    int cur = 0;
    for (int kk = 0; kk < K; kk += 32) {
        if (kk + 32 < K) stage(kk + 32, cur ^ 1);   // flies under MFMA below

        bf16x8 a[4], b[4];
#pragma unroll
        for (int i = 0; i < 4; i++)
            a[i] = *(const bf16x8*)(As[cur] + (wy * 64 + 16 * i + r16) * 32 + quad * 8);
#pragma unroll
        for (int j = 0; j < 4; j++)
            b[j] = *(const bf16x8*)(Bs[cur] + (wx * 64 + 16 * j + r16) * 32 + quad * 8);
#pragma unroll
        for (int i = 0; i < 4; i++)
#pragma unroll
            for (int j = 0; j < 4; j++)
                acc[i][j] = MFMA(a[i], b[j], acc[i][j]);
        __syncthreads();   // drains stage(t+1); guards buf reuse
        cur ^= 1;
    }

#pragma unroll
    for (int j = 0; j < 4; j++) {
        const int col = n0 + wx * 64 + 16 * j + r16;
        const float bv = bias ? bias[col] : 0.0f;
#pragma unroll
        for (int i = 0; i < 4; i++) {
#pragma unroll
            for (int r = 0; r < 4; r++) {
                const int row = m0 + wy * 64 + 16 * i + quad * 4 + r;
                const float v = acc[i][j][r] + bv;
                if constexpr (sizeof(CT) == 2) C[(long long)row * ldc + col] = f2b(v);
                else                           C[(long long)row * ldc + col] = v;
            }
        }
    }
}

// ---------------------------------------------------------------------------
// gemm_out v2 (2-phase dbuf): out[n,o] = sum_c u_b[n,c]*Ft[o,c] + bo[o].
// 128x256 tile (u_b read once), K=256, grid (128, 1, 4). 48 KB LDS.
// ---------------------------------------------------------------------------
__global__ __launch_bounds__(256) void gemm_out(
    const u16* __restrict__ Au, const u16* __restrict__ Ft,
    float* __restrict__ C, const float* __restrict__ bias)
{
    __shared__ u16 As[2][128 * 32];   // 16 KB
    __shared__ u16 Bs[2][256 * 32];   // 32 KB

    const int b = blockIdx.z;
    Au += (long long)b * NTOT * CC;
    const u16* Bm = Ft + (long long)b * 65536;
    C += (long long)b * NTOT * OUTC;

    const int m0 = blockIdx.x * 128;
    const int t  = threadIdx.x;
    const int wv = t >> 6, l = t & 63;
    const int wy = wv >> 1, wx = wv & 1;
    const int r16  = l & 15;
    const int quad = l >> 4;
    const int srow = wv * 16 + (l >> 2);
    const int scol = (l & 3) * 8;

    auto stage = [&](int kk, int buf) {
#pragma unroll
        for (int s = 0; s < 2; s++)
            GLD(Au + (long long)(m0 + s * 64 + srow) * CC + kk + scol,
                As[buf] + s * 2048 + wv * 512);
#pragma unroll
        for (int s = 0; s < 4; s++)
            GLD(Bm + (long long)(s * 64 + srow) * 256 + kk + scol,
                Bs[buf] + s * 2048 + wv * 512);
    };

    f32x4 acc[4][8] = {};

    stage(0, 0);
    __syncthreads();
    int cur = 0;
    for (int kk = 0; kk < 256; kk += 32) {
        if (kk + 32 < 256) stage(kk + 32, cur ^ 1);

        bf16x8 a[4], bb[8];
#pragma unroll
        for (int i = 0; i < 4; i++)
            a[i] = *(const bf16x8*)(As[cur] + (wy * 64 + 16 * i + r16) * 32 + quad * 8);
#pragma unroll
        for (int j = 0; j < 8; j++)
            bb[j] = *(const bf16x8*)(Bs[cur] + (wx * 128 + 16 * j + r16) * 32 + quad * 8);
#pragma unroll
        for (int i = 0; i < 4; i++)
#pragma unroll
            for (int j = 0; j < 8; j++)
                acc[i][j] = MFMA(a[i], bb[j], acc[i][j]);
        __syncthreads();
        cur ^= 1;
    }

#pragma unroll
    for (int j = 0; j < 8; j++) {
        const int col = wx * 128 + 16 * j + r16;
        const float bv = bias[col];
#pragma unroll
        for (int i = 0; i < 4; i++) {
#pragma unroll
            for (int r = 0; r < 4; r++) {
                const int row = m0 + wy * 64 + 16 * i + quad * 4 + r;
                C[(long long)row * OUTC + col] = acc[i][j][r] + bv;
            }
        }
    }
}

// ---------------------------------------------------------------------------
extern "C" void kernel_launch(void* const* d_in, const int* in_sizes, int n_in,
                              void* d_out, int out_size, void* d_ws, size_t ws_size,
                              hipStream_t stream)
{
    const float* u_src = (const float*)d_in[0];
    // d_in[1] = pos_src (unused)
    const float* Wq = (const float*)d_in[2];
    const float* Wk = (const float*)d_in[3];
    const float* Wv = (const float*)d_in[4];
    const float* Wo = (const float*)d_in[5];
    const float* bo = (const float*)d_in[6];
    float* out = (float*)d_out;

    char* ws = (char*)d_ws;
    size_t off = 0;
    float* Gp  = (float*)(ws + off); off += 67108864;  // [256][256][256] f32 partials
    float* suP = (float*)(ws + off); off += 262144;    // [256][256] f32
    u16*  Gb   = (u16*)(ws + off);  off += 524288;     // [4][256][256] bf16
    u16*  Wq_b = (u16*)(ws + off);  off += 262144;
    u16*  Wk_b = (u16*)(ws + off);  off += 262144;     // adjacent to Wv_b -> stacked [1024][256]
    u16*  Wv_b = (u16*)(ws + off);  off += 262144;
    u16*  Wo_b = (u16*)(ws + off);  off += 262144;     // [256][512] bf16
    float* su  = (float*)(ws + off); off += 4096;      // [4][256] f32
    u16*  Zt   = (u16*)(ws + off);  off += 1048576;    // [4][256][512] bf16
    u16*  Ft   = (u16*)(ws + off);  off += 524288;     // [4][256][256] bf16
    u16*  P2   = (u16*)(ws + off);  off += 2097152;    // [4][1024][256] bf16 ([Wk;Wv] x G)
    u16*  u_b  = (u16*)(ws + off);  off += 33554432;   // [4][16384][256] bf16 (side product)

    const dim3 blk(256);

    // weights -> bf16
    wcvt<<<dim3(64, 1, 4), blk, 0, stream>>>(Wq, Wk, Wv, Wo, Wq_b, Wk_b, Wv_b, Wo_b);

    // G partials from f32 u (cvt+transpose in staging) + su partials + u_b emit
    // 512 blocks x 256 thr: 2 halves per chunk -> 2 blocks/CU co-resident
    ggemm<<<dim3(512), blk, 0, stream>>>(u_src, Gp, suP, u_b);
    gred<<<dim3(64, BB), blk, 0, stream>>>(Gp, suP, Gb, su);

    // P2[b] = [Wk;Wv]_stacked (1024x256) x G_b (G symmetric -> B^T form exact)
    gemm_bt<u16><<<dim3(8, 2, BB), blk, 0, stream>>>(
        Wk_b, Gb, P2, nullptr, 256, 256, 256, 0, 65536, 262144);

    // stats/S/kv/Zt (short serial tail)
    skvz<<<dim3(BB * HH), blk, 0, stream>>>(P2, su, Wk_b, Wv_b, Wq_b, Zt);

    // Ft[b] = Wo Zt_b^T : [256x512]x[512x256]
    gemm_bt<u16><<<dim3(2, 2, BB), blk, 0, stream>>>(
        Wo_b, Zt, Ft, nullptr, 512, 512, 256, 0, 131072, 65536);

    // out = u_b Ft^T + bo (bf16 A via GLD, 2-phase, full-width tile)
    gemm_out<<<dim3(128, 1, BB), blk, 0, stream>>>(u_b, Ft, out, bo);
}

// Round 6
// 211.427 us; speedup vs baseline: 1.0991x; 1.0991x over previous
//
#include <hip/hip_runtime.h>
#include <hip/hip_bf16.h>

// Problem constants (from reference setup_inputs)
#define BB    4
#define NTOT  16384
#define CC    256
#define HH    8
#define DD    64
#define HD    512
#define OUTC  256

typedef unsigned short u16;
typedef unsigned int u32;
typedef __attribute__((ext_vector_type(8))) short bf16x8;   // 8 bf16 in 4 VGPRs
typedef __attribute__((ext_vector_type(4))) float f32x4;
typedef __attribute__((ext_vector_type(4))) short u16x4;
typedef __attribute__((ext_vector_type(4))) u32 u32x4;

__device__ __forceinline__ float b2f(u16 u) {
    union { float f; u32 i; } x; x.i = ((u32)u) << 16; return x.f;
}
__device__ __forceinline__ u16 f2b(float f) {
    union { float f; u32 i; } x; x.f = f;
    u32 r = x.i + 0x7fffu + ((x.i >> 16) & 1u);   // round-to-nearest-even
    return (u16)(r >> 16);
}

#define GLD(gp, lp) __builtin_amdgcn_global_load_lds( \
    (const __attribute__((address_space(1))) void*)(gp), \
    (__attribute__((address_space(3))) void*)(lp), 16, 0, 0)

#define MFMA(a, b, c) __builtin_amdgcn_mfma_f32_16x16x32_bf16((a), (b), (c), 0, 0, 0)

// ---------------------------------------------------------------------------
// wcvt: 4 weight matrices (each 131072 f32) -> bf16. grid (64, 1, 4).
// ---------------------------------------------------------------------------
__global__ __launch_bounds__(256) void wcvt(
    const float* __restrict__ Wq, const float* __restrict__ Wk,
    const float* __restrict__ Wv, const float* __restrict__ Wo,
    u16* __restrict__ q, u16* __restrict__ k,
    u16* __restrict__ v, u16* __restrict__ o)
{
    const int z = blockIdx.z;
    const float* src = z == 0 ? Wq : z == 1 ? Wk : z == 2 ? Wv : Wo;
    u16* dst = z == 0 ? q : z == 1 ? k : z == 2 ? v : o;
    const int i = (blockIdx.x * 256 + threadIdx.x) * 8;
    const float4 a = *(const float4*)(src + i);
    const float4 b = *(const float4*)(src + i + 4);
    union { bf16x8 v; u16 s[8]; } w;
    w.s[0] = f2b(a.x); w.s[1] = f2b(a.y); w.s[2] = f2b(a.z); w.s[3] = f2b(a.w);
    w.s[4] = f2b(b.x); w.s[5] = f2b(b.y); w.s[6] = f2b(b.z); w.s[7] = f2b(b.w);
    *(bf16x8*)(dst + i) = w.v;
}

// ---------------------------------------------------------------------------
// ggemm v4 (proven, r2 = 42.8us): Gp[z][i][j] = sum_{n in chunk} bf16(u)*bf16(u)
// + u_b side product. 512 thr, single Ts, 2 barriers/iter, 9-stride scatter.
// ---------------------------------------------------------------------------
__global__ __launch_bounds__(512) void ggemm(
    const float* __restrict__ u, float* __restrict__ Gp, float* __restrict__ suP,
    u16* __restrict__ u_b)
{
    __shared__ u32 Ts[16 * 290];   // 18.6 KB
    const int z = blockIdx.x, b = z >> 6, ck = z & 63;
    const float* base = u + (long long)b * NTOT * CC + (long long)ck * 256 * CC;
    u16* ub_base = u_b + (long long)b * NTOT * CC + (long long)ck * 256 * CC;
    const int t = threadIdx.x, w = t >> 6, l = t & 63;
    const int wy = w >> 1, wx = w & 1;
    const int r16 = l & 15, quad = l >> 4;
    const int sp = t >> 5;          // n-pair 0..15
    const int sq = t & 31;          // c-octet 0..31

    const int csa0 = 9 * ((wy * 64 + r16) >> 3) + (r16 & 7);     // + 18*i
    const int csb0 = 9 * ((wx * 128 + r16) >> 3) + (r16 & 7);    // + 18*j
    const int pr0 = 4 * quad * 290;

    f32x4 acc[4][8] = {};
    float su = 0.f;

    float4 a0, a1, b0, b1;
    {
        const float* src = base + (long long)(2 * sp) * CC + sq * 8;
        a0 = *(const float4*)src;       a1 = *(const float4*)(src + 4);
        b0 = *(const float4*)(src + CC); b1 = *(const float4*)(src + CC + 4);
    }

    for (int it = 0; it < 8; it++) {
        __syncthreads();   // prev iter's LDS reads complete (no-op first iter)
        {   // cvt rows, emit u_b, pair-pack + scatter-write (conflict-free)
            union { bf16x8 v; u16 q[8]; } ra, rb;
            ra.q[0] = f2b(a0.x); ra.q[1] = f2b(a0.y); ra.q[2] = f2b(a0.z); ra.q[3] = f2b(a0.w);
            ra.q[4] = f2b(a1.x); ra.q[5] = f2b(a1.y); ra.q[6] = f2b(a1.z); ra.q[7] = f2b(a1.w);
            rb.q[0] = f2b(b0.x); rb.q[1] = f2b(b0.y); rb.q[2] = f2b(b0.z); rb.q[3] = f2b(b0.w);
            rb.q[4] = f2b(b1.x); rb.q[5] = f2b(b1.y); rb.q[6] = f2b(b1.z); rb.q[7] = f2b(b1.w);
            {   // side-product: bf16 u rows (posted stores, nothing waits)
                u16* ub = ub_base + (long long)(it * 32 + 2 * sp) * CC + sq * 8;
                *(bf16x8*)ub = ra.v;
                *(bf16x8*)(ub + CC) = rb.v;
            }
            u32 pk[8];
#pragma unroll
            for (int k = 0; k < 8; k++)
                pk[k] = (u32)ra.q[k] | ((u32)rb.q[k] << 16);
            u32* dst = Ts + sp * 290 + 9 * sq;
#pragma unroll
            for (int k = 0; k < 8; k++) dst[k] = pk[k];
        }
        if (it < 7) {   // prefetch next 32-n slab (overlaps barrier+compute)
            const float* src = base + (long long)((it + 1) * 32 + 2 * sp) * CC + sq * 8;
            a0 = *(const float4*)src;       a1 = *(const float4*)(src + 4);
            b0 = *(const float4*)(src + CC); b1 = *(const float4*)(src + CC + 4);
        }
        __syncthreads();

        if (t < 256) {   // su partial for channel c = t
            const int cs = 9 * (t >> 3) + (t & 7);
            float s1 = 0.f;
#pragma unroll
            for (int p = 0; p < 16; p++) {
                u32 v = Ts[p * 290 + cs];
                s1 += b2f((u16)(v & 0xffff)) + b2f((u16)(v >> 16));
            }
            su += s1;
        }

        bf16x8 a[4], bb[8];
#pragma unroll
        for (int i = 0; i < 4; i++) {
            const int cs = csa0 + 18 * i;
            union { u32x4 u4; bf16x8 h; } f;
            f.u4[0] = Ts[pr0 + cs];       f.u4[1] = Ts[pr0 + 290 + cs];
            f.u4[2] = Ts[pr0 + 580 + cs]; f.u4[3] = Ts[pr0 + 870 + cs];
            a[i] = f.h;
        }
#pragma unroll
        for (int j = 0; j < 8; j++) {
            const int cs = csb0 + 18 * j;
            union { u32x4 u4; bf16x8 h; } f;
            f.u4[0] = Ts[pr0 + cs];       f.u4[1] = Ts[pr0 + 290 + cs];
            f.u4[2] = Ts[pr0 + 580 + cs]; f.u4[3] = Ts[pr0 + 870 + cs];
            bb[j] = f.h;
        }
#pragma unroll
        for (int i = 0; i < 4; i++)
#pragma unroll
            for (int j = 0; j < 8; j++)
                acc[i][j] = MFMA(a[i], bb[j], acc[i][j]);
    }

    float* Cp = Gp + (long long)z * 65536;
#pragma unroll
    for (int i = 0; i < 4; i++)
#pragma unroll
        for (int j = 0; j < 8; j++)
#pragma unroll
            for (int rr = 0; rr < 4; rr++)
                Cp[(wy * 64 + 16 * i + quad * 4 + rr) * 256 + wx * 128 + 16 * j + r16]
                    = acc[i][j][rr];
    if (t < 256) suP[z * 256 + t] = su;
}

// ---------------------------------------------------------------------------
// gred: Gb[b][i][j] = bf16(sum_{ck<64} Gp), f32x4 per thread (4 cols).
// grid (64, 4), 256 thr; block x==0 also reduces suP -> su.
// ---------------------------------------------------------------------------
__global__ __launch_bounds__(256) void gred(
    const float* __restrict__ Gp, const float* __restrict__ suP,
    u16* __restrict__ Gb, float* __restrict__ su)
{
    const int b = blockIdx.y, t = threadIdx.x;
    const int row = blockIdx.x * 4 + (t >> 6);
    const int col = (t & 63) * 4;
    const float* p = Gp + (long long)(b * 64) * 65536 + row * 256 + col;
    f32x4 s = {};
#pragma unroll
    for (int ck = 0; ck < 64; ck++) {
        f32x4 v = *(const f32x4*)(p + (long long)ck * 65536);
        s[0] += v[0]; s[1] += v[1]; s[2] += v[2]; s[3] += v[3];
    }
    union { u16x4 v; u16 q[4]; } pk;
#pragma unroll
    for (int k = 0; k < 4; k++) pk.q[k] = f2b(s[k]);
    *(u16x4*)(Gb + (long long)b * 65536 + row * 256 + col) = pk.v;

    if (blockIdx.x == 0) {
        float s2 = 0.f;
#pragma unroll
        for (int ck = 0; ck < 64; ck++) s2 += suP[(b * 64 + ck) * 256 + t];
        su[b * 256 + t] = s2;
    }
}

// ---------------------------------------------------------------------------
// skvz: serial tail per (b,h). Inputs: P2 = [Wk;Wv]_stacked x G (bf16), su.
// stats via direct row-dots; S = Pk Wv^T (frags from global); kv -> kvT LDS;
// WqT staging + Y-phase. grid (32), 256 thr.
// ---------------------------------------------------------------------------
__global__ __launch_bounds__(256) void skvz(
    const u16* __restrict__ P2, const float* __restrict__ su,
    const u16* __restrict__ Wk_b, const u16* __restrict__ Wv_b,
    const u16* __restrict__ Wq_b, u16* __restrict__ Zt)
{
    __shared__ u16 pool[20480];   // kvTL 8KB + WqTL 32KB
    __shared__ float mkL[64], rkL[64], mvL[64], rvL[64];

    const int bx = blockIdx.x, b = bx >> 3, h = bx & 7;
    const int t = threadIdx.x, w = t >> 6, l = t & 63;
    const int r16 = l & 15, quad = l >> 4;

    const u16* WkH = Wk_b + (h * 64) * 256;
    const u16* WvH = Wv_b + (h * 64) * 256;
    const u16* PkH = P2 + (long long)b * 262144 + (h * 64) * 256;
    const u16* PvH = P2 + (long long)b * 262144 + (512 + h * 64) * 256;

    // ---- stats: 2 threads per row (128 rows: 64 k + 64 v) ----
    {
        const int row = t >> 1, half = t & 1;
        const u16* Prow = (row < 64 ? PkH + row * 256 : PvH + (row - 64) * 256) + half * 128;
        const u16* Wrow = (row < 64 ? WkH + row * 256 : WvH + (row - 64) * 256) + half * 128;
        const float* suB = su + b * 256 + half * 128;
        float e2 = 0.f, m = 0.f;
#pragma unroll
        for (int c8 = 0; c8 < 16; c8++) {
            bf16x8 pw = *(const bf16x8*)(Prow + c8 * 8);
            bf16x8 ww = *(const bf16x8*)(Wrow + c8 * 8);
#pragma unroll
            for (int k = 0; k < 8; k++) {
                const float wv_ = b2f((u16)ww[k]);
                e2 += b2f((u16)pw[k]) * wv_;
                m  += wv_ * suB[c8 * 8 + k];
            }
        }
        e2 += __shfl_xor(e2, 1);
        m  += __shfl_xor(m, 1);
        if (half == 0) {
            m *= (1.0f / NTOT);
            const float r = rsqrtf(e2 * (1.0f / NTOT) - m * m + 1e-5f);
            if (row < 64) { mkL[row] = m; rkL[row] = r; }
            else          { mvL[row - 64] = m; rvL[row - 64] = r; }
        }
    }
    __syncthreads();

    // ---- S-phase: S[d,e] = sum_c Pk[d,c] Wv[e,c]; frags from global ----
    const int mh = (w >> 1) * 32, nh = (w & 1) * 32;
    float mkR[2][4], rkR[2][4], mvR[2], rvR[2];
#pragma unroll
    for (int i = 0; i < 2; i++)
#pragma unroll
        for (int rr = 0; rr < 4; rr++) {
            mkR[i][rr] = mkL[mh + 16 * i + quad * 4 + rr];
            rkR[i][rr] = rkL[mh + 16 * i + quad * 4 + rr];
        }
#pragma unroll
    for (int j = 0; j < 2; j++) {
        mvR[j] = mvL[nh + 16 * j + r16];
        rvR[j] = rvL[nh + 16 * j + r16];
    }

    f32x4 accs[2][2] = {};
    for (int ch = 0; ch < 8; ch++) {
        const int ko = quad * 8;
        bf16x8 ap[2], bv[2];
#pragma unroll
        for (int i = 0; i < 2; i++)
            ap[i] = *(const bf16x8*)(PkH + (mh + 16 * i + r16) * 256 + ch * 32 + ko);
#pragma unroll
        for (int j = 0; j < 2; j++)
            bv[j] = *(const bf16x8*)(WvH + (nh + 16 * j + r16) * 256 + ch * 32 + ko);
#pragma unroll
        for (int i = 0; i < 2; i++)
#pragma unroll
            for (int j = 0; j < 2; j++)
                accs[i][j] = MFMA(ap[i], bv[j], accs[i][j]);
    }

    // ---- kv -> kvTL; WqTL ----
    u16* kvTL = pool;            // 8 KB
    u16* WqTL = pool + 4096;     // 32 KB
#pragma unroll
    for (int i = 0; i < 2; i++)
#pragma unroll
        for (int j = 0; j < 2; j++)
#pragma unroll
            for (int rr = 0; rr < 4; rr++) {
                const int d = mh + 16 * i + quad * 4 + rr;
                const int e = nh + 16 * j + r16;
                const float kv = rkR[i][rr] * rvR[j] *
                    (accs[i][j][rr] * (1.0f / NTOT) - mkR[i][rr] * mvR[j]);
                kvTL[(d >> 5) * 2048 + e * 32 + (d & 31)] = f2b(kv);
            }
    {
        const int d = t >> 2, q = t & 3;
        const u16* Wrow = Wq_b + (h * 64 + d) * 256 + q * 64;
#pragma unroll
        for (int s = 0; s < 8; s++) {
            bf16x8 raw = *(const bf16x8*)(Wrow + s * 8);
#pragma unroll
            for (int k = 0; k < 8; k++) {
                const int c = q * 64 + s * 8 + k;
                WqTL[(d >> 5) * 8192 + c * 32 + (d & 31)] = (u16)raw[k];
            }
        }
    }
    __syncthreads();

    // ---- Y-phase ----
    f32x4 accy[4][4] = {};
#pragma unroll
    for (int ch = 0; ch < 2; ch++) {
        const int ko = quad * 8;
        bf16x8 akv[4], bq[4];
#pragma unroll
        for (int i = 0; i < 4; i++)
            akv[i] = *(const bf16x8*)(kvTL + ch * 2048 + (16 * i + r16) * 32 + ko);
#pragma unroll
        for (int j = 0; j < 4; j++)
            bq[j] = *(const bf16x8*)(WqTL + ch * 8192 + (w * 64 + 16 * j + r16) * 32 + ko);
#pragma unroll
        for (int i = 0; i < 4; i++)
#pragma unroll
            for (int j = 0; j < 4; j++)
                accy[i][j] = MFMA(akv[i], bq[j], accy[i][j]);
    }
#pragma unroll
    for (int i = 0; i < 4; i++)
#pragma unroll
        for (int j = 0; j < 4; j++) {
            const int c = w * 64 + 16 * j + r16;
            const int e0 = 16 * i + quad * 4;
            union { u16x4 v; u16 s[4]; } pk;
#pragma unroll
            for (int rr = 0; rr < 4; rr++) pk.s[rr] = f2b(accy[i][j][rr]);
            *(u16x4*)(Zt + ((long long)(b * 256 + c)) * 512 + h * 64 + e0) = pk.v;
        }
}

// ---------------------------------------------------------------------------
// gemm_bt (proven, r2): C[m,n] = sum_k A[m,k]*Bm[n,k] (+bias[n]); bf16 A,B.
// ---------------------------------------------------------------------------
template <typename CT>
__global__ __launch_bounds__(256) void gemm_bt(
    const u16* __restrict__ A, const u16* __restrict__ Bm,
    CT* __restrict__ C, const float* __restrict__ bias,
    int K, int lda, int ldc,
    long long aStride, long long bStride, long long cStride)
{
    __shared__ u16 As[128 * 32];
    __shared__ u16 Bs[128 * 32];

    const int bz = blockIdx.z;
    A  += (long long)bz * aStride;
    Bm += (long long)bz * bStride;
    C  += (long long)bz * cStride;

    const int m0 = blockIdx.x * 128;
    const int n0 = blockIdx.y * 128;
    const int t  = threadIdx.x;
    const int wv = t >> 6, l = t & 63;
    const int wy = wv >> 1, wx = wv & 1;
    const int r16  = l & 15;
    const int quad = l >> 4;
    const int srow = wv * 16 + (l >> 2);
    const int scol = (l & 3) * 8;

    f32x4 acc[4][4] = {};

    for (int kk = 0; kk < K; kk += 32) {
#pragma unroll
        for (int s = 0; s < 2; s++) {
            GLD(A + (long long)(m0 + s * 64 + srow) * lda + kk + scol,
                As + s * 2048 + wv * 512);
            GLD(Bm + (long long)(n0 + s * 64 + srow) * K + kk + scol,
                Bs + s * 2048 + wv * 512);
        }
        __syncthreads();

        bf16x8 a[4], b[4];
#pragma unroll
        for (int i = 0; i < 4; i++)
            a[i] = *(const bf16x8*)(As + (wy * 64 + 16 * i + r16) * 32 + quad * 8);
#pragma unroll
        for (int j = 0; j < 4; j++)
            b[j] = *(const bf16x8*)(Bs + (wx * 64 + 16 * j + r16) * 32 + quad * 8);
#pragma unroll
        for (int i = 0; i < 4; i++)
#pragma unroll
            for (int j = 0; j < 4; j++)
                acc[i][j] = MFMA(a[i], b[j], acc[i][j]);
        __syncthreads();
    }

#pragma unroll
    for (int j = 0; j < 4; j++) {
        const int col = n0 + wx * 64 + 16 * j + r16;
        const float bv = bias ? bias[col] : 0.0f;
#pragma unroll
        for (int i = 0; i < 4; i++) {
#pragma unroll
            for (int r = 0; r < 4; r++) {
                const int row = m0 + wy * 64 + 16 * i + quad * 4 + r;
                const float v = acc[i][j][r] + bv;
                if constexpr (sizeof(CT) == 2) C[(long long)row * ldc + col] = f2b(v);
                else                           C[(long long)row * ldc + col] = v;
            }
        }
    }
}

// ---------------------------------------------------------------------------
// gemm_out v3: out[n,o] = sum_c u_b[n,c]*Ft[o,c] + bo[o], f32 out.
// OCCUPANCY FIX: 1024 thr, 16 waves (4x4), 32x64 per wave -> acc[2][4] =
// only 32 acc regs/thread (~100 total <= 128 -> 4 waves/SIMD -> whole block
// resident, 50% occupancy vs 8.8% of the 256-thr/128-acc version).
// Same 128x256 tile (u_b read once), same GLD staging (dest = 16*t bytes,
// linear), bitwise-identical MFMA k-order. grid (128, 1, 4). 24 KB LDS.
// ---------------------------------------------------------------------------
__global__ __launch_bounds__(1024) void gemm_out(
    const u16* __restrict__ Au, const u16* __restrict__ Ft,
    float* __restrict__ C, const float* __restrict__ bias)
{
    __shared__ u16 As[128 * 32];   // 8 KB
    __shared__ u16 Bs[256 * 32];   // 16 KB

    const int b = blockIdx.z;
    Au += (long long)b * NTOT * CC;
    const u16* Bm = Ft + (long long)b * 65536;
    C += (long long)b * NTOT * OUTC;

    const int m0 = blockIdx.x * 128;
    const int t  = threadIdx.x;
    const int wv = t >> 6, l = t & 63;
    const int wy = wv >> 2, wx = wv & 3;   // 4x4 wave grid, 32x64 each
    const int r16  = l & 15;
    const int quad = l >> 4;
    const int srow = t >> 2;               // staging row
    const int scol = (t & 3) * 8;          // staging col (8 bf16 = 16 B)

    f32x4 acc[2][4] = {};

    for (int kk = 0; kk < 256; kk += 32) {
        // B: 256x32 staged by all 1024 thr (1 GLD, dest byte = 16*t: linear)
        GLD(Bm + (long long)srow * 256 + kk + scol, Bs + srow * 32 + scol);
        // A: 128x32 staged by waves 0..7 (t<512; wave-uniform branch)
        if (t < 512)
            GLD(Au + (long long)(m0 + srow) * CC + kk + scol, As + srow * 32 + scol);
        __syncthreads();

        bf16x8 a[2], bb[4];
#pragma unroll
        for (int i = 0; i < 2; i++)
            a[i] = *(const bf16x8*)(As + (wy * 32 + 16 * i + r16) * 32 + quad * 8);
#pragma unroll
        for (int j = 0; j < 4; j++)
            bb[j] = *(const bf16x8*)(Bs + (wx * 64 + 16 * j + r16) * 32 + quad * 8);
#pragma unroll
        for (int i = 0; i < 2; i++)
#pragma unroll
            for (int j = 0; j < 4; j++)
                acc[i][j] = MFMA(a[i], bb[j], acc[i][j]);
        __syncthreads();
    }

#pragma unroll
    for (int j = 0; j < 4; j++) {
        const int col = wx * 64 + 16 * j + r16;
        const float bv = bias[col];
#pragma unroll
        for (int i = 0; i < 2; i++) {
#pragma unroll
            for (int r = 0; r < 4; r++) {
                const int row = m0 + wy * 32 + 16 * i + quad * 4 + r;
                C[(long long)row * OUTC + col] = acc[i][j][r] + bv;
            }
        }
    }
}

// ---------------------------------------------------------------------------
extern "C" void kernel_launch(void* const* d_in, const int* in_sizes, int n_in,
                              void* d_out, int out_size, void* d_ws, size_t ws_size,
                              hipStream_t stream)
{
    const float* u_src = (const float*)d_in[0];
    // d_in[1] = pos_src (unused)
    const float* Wq = (const float*)d_in[2];
    const float* Wk = (const float*)d_in[3];
    const float* Wv = (const float*)d_in[4];
    const float* Wo = (const float*)d_in[5];
    const float* bo = (const float*)d_in[6];
    float* out = (float*)d_out;

    char* ws = (char*)d_ws;
    size_t off = 0;
    float* Gp  = (float*)(ws + off); off += 67108864;  // [256][256][256] f32 partials
    float* suP = (float*)(ws + off); off += 262144;    // [256][256] f32
    u16*  Gb   = (u16*)(ws + off);  off += 524288;     // [4][256][256] bf16
    u16*  Wq_b = (u16*)(ws + off);  off += 262144;
    u16*  Wk_b = (u16*)(ws + off);  off += 262144;     // adjacent to Wv_b -> stacked [1024][256]
    u16*  Wv_b = (u16*)(ws + off);  off += 262144;
    u16*  Wo_b = (u16*)(ws + off);  off += 262144;     // [256][512] bf16
    float* su  = (float*)(ws + off); off += 4096;      // [4][256] f32
    u16*  Zt   = (u16*)(ws + off);  off += 1048576;    // [4][256][512] bf16
    u16*  Ft   = (u16*)(ws + off);  off += 524288;     // [4][256][256] bf16
    u16*  P2   = (u16*)(ws + off);  off += 2097152;    // [4][1024][256] bf16 ([Wk;Wv] x G)
    u16*  u_b  = (u16*)(ws + off);  off += 33554432;   // [4][16384][256] bf16 (side product)

    const dim3 blk(256);

    // weights -> bf16
    wcvt<<<dim3(64, 1, 4), blk, 0, stream>>>(Wq, Wk, Wv, Wo, Wq_b, Wk_b, Wv_b, Wo_b);

    // G partials from f32 u (cvt+transpose in staging) + su partials + u_b emit
    ggemm<<<dim3(BB * 64), dim3(512), 0, stream>>>(u_src, Gp, suP, u_b);
    gred<<<dim3(64, BB), blk, 0, stream>>>(Gp, suP, Gb, su);

    // P2[b] = [Wk;Wv]_stacked (1024x256) x G_b (G symmetric -> B^T form exact)
    gemm_bt<u16><<<dim3(8, 2, BB), blk, 0, stream>>>(
        Wk_b, Gb, P2, nullptr, 256, 256, 256, 0, 65536, 262144);

    // stats/S/kv/Zt (short serial tail)
    skvz<<<dim3(BB * HH), blk, 0, stream>>>(P2, su, Wk_b, Wv_b, Wq_b, Zt);

    // Ft[b] = Wo Zt_b^T : [256x512]x[512x256]
    gemm_bt<u16><<<dim3(2, 2, BB), blk, 0, stream>>>(
        Wo_b, Zt, Ft, nullptr, 512, 512, 256, 0, 131072, 65536);

    // out = u_b Ft^T + bo (bf16 A via GLD, 16-wave low-acc block)
    gemm_out<<<dim3(128, 1, BB), dim3(1024), 0, stream>>>(u_b, Ft, out, bo);
}

// Round 7
// 210.442 us; speedup vs baseline: 1.1043x; 1.0047x over previous
//
#include <hip/hip_runtime.h>
#include <hip/hip_bf16.h>

// Problem constants (from reference setup_inputs)
#define BB    4
#define NTOT  16384
#define CC    256
#define HH    8
#define DD    64
#define HD    512
#define OUTC  256

typedef unsigned short u16;
typedef unsigned int u32;
typedef __attribute__((ext_vector_type(8))) short bf16x8;   // 8 bf16 in 4 VGPRs
typedef __attribute__((ext_vector_type(4))) float f32x4;
typedef __attribute__((ext_vector_type(4))) short u16x4;
typedef __attribute__((ext_vector_type(4))) u32 u32x4;

__device__ __forceinline__ float b2f(u16 u) {
    union { float f; u32 i; } x; x.i = ((u32)u) << 16; return x.f;
}
__device__ __forceinline__ u16 f2b(float f) {
    union { float f; u32 i; } x; x.f = f;
    u32 r = x.i + 0x7fffu + ((x.i >> 16) & 1u);   // round-to-nearest-even
    return (u16)(r >> 16);
}

#define GLD(gp, lp) __builtin_amdgcn_global_load_lds( \
    (const __attribute__((address_space(1))) void*)(gp), \
    (__attribute__((address_space(3))) void*)(lp), 16, 0, 0)

#define MFMA(a, b, c) __builtin_amdgcn_mfma_f32_16x16x32_bf16((a), (b), (c), 0, 0, 0)

// ---------------------------------------------------------------------------
// wcvt: 4 weight matrices (each 131072 f32) -> bf16. grid (64, 1, 4).
// ---------------------------------------------------------------------------
__global__ __launch_bounds__(256) void wcvt(
    const float* __restrict__ Wq, const float* __restrict__ Wk,
    const float* __restrict__ Wv, const float* __restrict__ Wo,
    u16* __restrict__ q, u16* __restrict__ k,
    u16* __restrict__ v, u16* __restrict__ o)
{
    const int z = blockIdx.z;
    const float* src = z == 0 ? Wq : z == 1 ? Wk : z == 2 ? Wv : Wo;
    u16* dst = z == 0 ? q : z == 1 ? k : z == 2 ? v : o;
    const int i = (blockIdx.x * 256 + threadIdx.x) * 8;
    const float4 a = *(const float4*)(src + i);
    const float4 b = *(const float4*)(src + i + 4);
    union { bf16x8 v; u16 s[8]; } w;
    w.s[0] = f2b(a.x); w.s[1] = f2b(a.y); w.s[2] = f2b(a.z); w.s[3] = f2b(a.w);
    w.s[4] = f2b(b.x); w.s[5] = f2b(b.y); w.s[6] = f2b(b.z); w.s[7] = f2b(b.w);
    *(bf16x8*)(dst + i) = w.v;
}

// ---------------------------------------------------------------------------
// ggemm v7: v4 structure + raw-barrier schedule. Per iter:
//   stage(Ts ds_writes + u_b posted stores) ; prefetch next slab (posted)
//   s_waitcnt lgkmcnt(0) ; s_barrier      <- Ts visible; vmcnt NOT drained:
//                                            u_b stores + prefetch loads FLY
//   frag reads + MFMA (compiler lgkm-waits cover read-after-write)
//   "" memory clobber ; s_barrier         <- reads consumed (MFMA deps force
//                                            lgkm waits before this point)
// su accumulated in registers (bit-identical bf16 values), reduced once via
// Ts scratch after the loop. grid (256), 512 thr.
// ---------------------------------------------------------------------------
__global__ __launch_bounds__(512) void ggemm(
    const float* __restrict__ u, float* __restrict__ Gp, float* __restrict__ suP,
    u16* __restrict__ u_b)
{
    __shared__ u32 Ts[16 * 290];   // 18.6 KB
    const int z = blockIdx.x, b = z >> 6, ck = z & 63;
    const float* base = u + (long long)b * NTOT * CC + (long long)ck * 256 * CC;
    u16* ub_base = u_b + (long long)b * NTOT * CC + (long long)ck * 256 * CC;
    const int t = threadIdx.x, w = t >> 6, l = t & 63;
    const int wy = w >> 1, wx = w & 1;
    const int r16 = l & 15, quad = l >> 4;
    const int sp = t >> 5;          // n-pair 0..15
    const int sq = t & 31;          // c-octet 0..31

    const int csa0 = 9 * ((wy * 64 + r16) >> 3) + (r16 & 7);     // + 18*i
    const int csb0 = 9 * ((wx * 128 + r16) >> 3) + (r16 & 7);    // + 18*j
    const int pr0 = 4 * quad * 290;

    f32x4 acc[4][8] = {};
    float su8[8] = {};

    float4 a0, a1, b0, b1;
    {
        const float* src = base + (long long)(2 * sp) * CC + sq * 8;
        a0 = *(const float4*)src;       a1 = *(const float4*)(src + 4);
        b0 = *(const float4*)(src + CC); b1 = *(const float4*)(src + CC + 4);
    }

    for (int it = 0; it < 8; it++) {
        {   // cvt rows, su8 reg-accumulate, emit u_b, pair-pack + scatter
            union { bf16x8 v; u16 q[8]; } ra, rb;
            ra.q[0] = f2b(a0.x); ra.q[1] = f2b(a0.y); ra.q[2] = f2b(a0.z); ra.q[3] = f2b(a0.w);
            ra.q[4] = f2b(a1.x); ra.q[5] = f2b(a1.y); ra.q[6] = f2b(a1.z); ra.q[7] = f2b(a1.w);
            rb.q[0] = f2b(b0.x); rb.q[1] = f2b(b0.y); rb.q[2] = f2b(b0.z); rb.q[3] = f2b(b0.w);
            rb.q[4] = f2b(b1.x); rb.q[5] = f2b(b1.y); rb.q[6] = f2b(b1.z); rb.q[7] = f2b(b1.w);
#pragma unroll
            for (int k = 0; k < 8; k++)
                su8[k] += b2f(ra.q[k]) + b2f(rb.q[k]);
            {   // side-product: bf16 u rows (posted stores; never waited on)
                u16* ub = ub_base + (long long)(it * 32 + 2 * sp) * CC + sq * 8;
                *(bf16x8*)ub = ra.v;
                *(bf16x8*)(ub + CC) = rb.v;
            }
            u32 pk[8];
#pragma unroll
            for (int k = 0; k < 8; k++)
                pk[k] = (u32)ra.q[k] | ((u32)rb.q[k] << 16);
            u32* dst = Ts + sp * 290 + 9 * sq;
#pragma unroll
            for (int k = 0; k < 8; k++) dst[k] = pk[k];
        }
        if (it < 7) {   // posted loads: fly across the lgkm-only barrier
            const float* src = base + (long long)((it + 1) * 32 + 2 * sp) * CC + sq * 8;
            a0 = *(const float4*)src;       a1 = *(const float4*)(src + 4);
            b0 = *(const float4*)(src + CC); b1 = *(const float4*)(src + CC + 4);
        }
        // Ts visibility barrier: drain LDS writes only (NOT vmcnt)
        asm volatile("s_waitcnt lgkmcnt(0)" ::: "memory");
        __builtin_amdgcn_s_barrier();

        bf16x8 a[4], bb[8];
#pragma unroll
        for (int i = 0; i < 4; i++) {
            const int cs = csa0 + 18 * i;
            union { u32x4 u4; bf16x8 h; } f;
            f.u4[0] = Ts[pr0 + cs];       f.u4[1] = Ts[pr0 + 290 + cs];
            f.u4[2] = Ts[pr0 + 580 + cs]; f.u4[3] = Ts[pr0 + 870 + cs];
            a[i] = f.h;
        }
#pragma unroll
        for (int j = 0; j < 8; j++) {
            const int cs = csb0 + 18 * j;
            union { u32x4 u4; bf16x8 h; } f;
            f.u4[0] = Ts[pr0 + cs];       f.u4[1] = Ts[pr0 + 290 + cs];
            f.u4[2] = Ts[pr0 + 580 + cs]; f.u4[3] = Ts[pr0 + 870 + cs];
            bb[j] = f.h;
        }
#pragma unroll
        for (int i = 0; i < 4; i++)
#pragma unroll
            for (int j = 0; j < 8; j++)
                acc[i][j] = MFMA(a[i], bb[j], acc[i][j]);
        // reads-consumed barrier: MFMA deps already forced lgkm waits;
        // clobber pins LDS ops on this side of the barrier.
        asm volatile("" ::: "memory");
        __builtin_amdgcn_s_barrier();
    }

    float* Cp = Gp + (long long)z * 65536;
#pragma unroll
    for (int i = 0; i < 4; i++)
#pragma unroll
        for (int j = 0; j < 8; j++)
#pragma unroll
            for (int rr = 0; rr < 4; rr++)
                Cp[(wy * 64 + 16 * i + quad * 4 + rr) * 256 + wx * 128 + 16 * j + r16]
                    = acc[i][j][rr];

    // ---- su reduce via Ts scratch (loop's trailing barrier guards reuse) ----
    float* S = (float*)Ts;   // [16][264] f32 = 16.9 KB < 18.6 KB
#pragma unroll
    for (int k = 0; k < 8; k++) S[sp * 264 + sq * 8 + k] = su8[k];
    __syncthreads();
    if (t < 256) {
        float s = 0.f;
#pragma unroll
        for (int p = 0; p < 16; p++) s += S[p * 264 + t];
        suP[z * 256 + t] = s;
    }
}

// ---------------------------------------------------------------------------
// gred: Gb[b][i][j] = bf16(sum_{ck<64} Gp), f32x4 per thread (4 cols).
// grid (64, 4), 256 thr; block x==0 also reduces suP -> su.
// ---------------------------------------------------------------------------
__global__ __launch_bounds__(256) void gred(
    const float* __restrict__ Gp, const float* __restrict__ suP,
    u16* __restrict__ Gb, float* __restrict__ su)
{
    const int b = blockIdx.y, t = threadIdx.x;
    const int row = blockIdx.x * 4 + (t >> 6);
    const int col = (t & 63) * 4;
    const float* p = Gp + (long long)(b * 64) * 65536 + row * 256 + col;
    f32x4 s = {};
#pragma unroll
    for (int ck = 0; ck < 64; ck++) {
        f32x4 v = *(const f32x4*)(p + (long long)ck * 65536);
        s[0] += v[0]; s[1] += v[1]; s[2] += v[2]; s[3] += v[3];
    }
    union { u16x4 v; u16 q[4]; } pk;
#pragma unroll
    for (int k = 0; k < 4; k++) pk.q[k] = f2b(s[k]);
    *(u16x4*)(Gb + (long long)b * 65536 + row * 256 + col) = pk.v;

    if (blockIdx.x == 0) {
        float s2 = 0.f;
#pragma unroll
        for (int ck = 0; ck < 64; ck++) s2 += suP[(b * 64 + ck) * 256 + t];
        su[b * 256 + t] = s2;
    }
}

// ---------------------------------------------------------------------------
// skvz: serial tail per (b,h). Inputs: P2 = [Wk;Wv]_stacked x G (bf16), su.
// stats via direct row-dots; S = Pk Wv^T (frags from global); kv -> kvT LDS;
// WqT staging + Y-phase. grid (32), 256 thr.
// ---------------------------------------------------------------------------
__global__ __launch_bounds__(256) void skvz(
    const u16* __restrict__ P2, const float* __restrict__ su,
    const u16* __restrict__ Wk_b, const u16* __restrict__ Wv_b,
    const u16* __restrict__ Wq_b, u16* __restrict__ Zt)
{
    __shared__ u16 pool[20480];   // kvTL 8KB + WqTL 32KB
    __shared__ float mkL[64], rkL[64], mvL[64], rvL[64];

    const int bx = blockIdx.x, b = bx >> 3, h = bx & 7;
    const int t = threadIdx.x, w = t >> 6, l = t & 63;
    const int r16 = l & 15, quad = l >> 4;

    const u16* WkH = Wk_b + (h * 64) * 256;
    const u16* WvH = Wv_b + (h * 64) * 256;
    const u16* PkH = P2 + (long long)b * 262144 + (h * 64) * 256;
    const u16* PvH = P2 + (long long)b * 262144 + (512 + h * 64) * 256;

    // ---- stats: 2 threads per row (128 rows: 64 k + 64 v) ----
    {
        const int row = t >> 1, half = t & 1;
        const u16* Prow = (row < 64 ? PkH + row * 256 : PvH + (row - 64) * 256) + half * 128;
        const u16* Wrow = (row < 64 ? WkH + row * 256 : WvH + (row - 64) * 256) + half * 128;
        const float* suB = su + b * 256 + half * 128;
        float e2 = 0.f, m = 0.f;
#pragma unroll
        for (int c8 = 0; c8 < 16; c8++) {
            bf16x8 pw = *(const bf16x8*)(Prow + c8 * 8);
            bf16x8 ww = *(const bf16x8*)(Wrow + c8 * 8);
#pragma unroll
            for (int k = 0; k < 8; k++) {
                const float wv_ = b2f((u16)ww[k]);
                e2 += b2f((u16)pw[k]) * wv_;
                m  += wv_ * suB[c8 * 8 + k];
            }
        }
        e2 += __shfl_xor(e2, 1);
        m  += __shfl_xor(m, 1);
        if (half == 0) {
            m *= (1.0f / NTOT);
            const float r = rsqrtf(e2 * (1.0f / NTOT) - m * m + 1e-5f);
            if (row < 64) { mkL[row] = m; rkL[row] = r; }
            else          { mvL[row - 64] = m; rvL[row - 64] = r; }
        }
    }
    __syncthreads();

    // ---- S-phase: S[d,e] = sum_c Pk[d,c] Wv[e,c]; frags from global ----
    const int mh = (w >> 1) * 32, nh = (w & 1) * 32;
    float mkR[2][4], rkR[2][4], mvR[2], rvR[2];
#pragma unroll
    for (int i = 0; i < 2; i++)
#pragma unroll
        for (int rr = 0; rr < 4; rr++) {
            mkR[i][rr] = mkL[mh + 16 * i + quad * 4 + rr];
            rkR[i][rr] = rkL[mh + 16 * i + quad * 4 + rr];
        }
#pragma unroll
    for (int j = 0; j < 2; j++) {
        mvR[j] = mvL[nh + 16 * j + r16];
        rvR[j] = rvL[nh + 16 * j + r16];
    }

    f32x4 accs[2][2] = {};
    for (int ch = 0; ch < 8; ch++) {
        const int ko = quad * 8;
        bf16x8 ap[2], bv[2];
#pragma unroll
        for (int i = 0; i < 2; i++)
            ap[i] = *(const bf16x8*)(PkH + (mh + 16 * i + r16) * 256 + ch * 32 + ko);
#pragma unroll
        for (int j = 0; j < 2; j++)
            bv[j] = *(const bf16x8*)(WvH + (nh + 16 * j + r16) * 256 + ch * 32 + ko);
#pragma unroll
        for (int i = 0; i < 2; i++)
#pragma unroll
            for (int j = 0; j < 2; j++)
                accs[i][j] = MFMA(ap[i], bv[j], accs[i][j]);
    }

    // ---- kv -> kvTL; WqTL ----
    u16* kvTL = pool;            // 8 KB
    u16* WqTL = pool + 4096;     // 32 KB
#pragma unroll
    for (int i = 0; i < 2; i++)
#pragma unroll
        for (int j = 0; j < 2; j++)
#pragma unroll
            for (int rr = 0; rr < 4; rr++) {
                const int d = mh + 16 * i + quad * 4 + rr;
                const int e = nh + 16 * j + r16;
                const float kv = rkR[i][rr] * rvR[j] *
                    (accs[i][j][rr] * (1.0f / NTOT) - mkR[i][rr] * mvR[j]);
                kvTL[(d >> 5) * 2048 + e * 32 + (d & 31)] = f2b(kv);
            }
    {
        const int d = t >> 2, q = t & 3;
        const u16* Wrow = Wq_b + (h * 64 + d) * 256 + q * 64;
#pragma unroll
        for (int s = 0; s < 8; s++) {
            bf16x8 raw = *(const bf16x8*)(Wrow + s * 8);
#pragma unroll
            for (int k = 0; k < 8; k++) {
                const int c = q * 64 + s * 8 + k;
                WqTL[(d >> 5) * 8192 + c * 32 + (d & 31)] = (u16)raw[k];
            }
        }
    }
    __syncthreads();

    // ---- Y-phase ----
    f32x4 accy[4][4] = {};
#pragma unroll
    for (int ch = 0; ch < 2; ch++) {
        const int ko = quad * 8;
        bf16x8 akv[4], bq[4];
#pragma unroll
        for (int i = 0; i < 4; i++)
            akv[i] = *(const bf16x8*)(kvTL + ch * 2048 + (16 * i + r16) * 32 + ko);
#pragma unroll
        for (int j = 0; j < 4; j++)
            bq[j] = *(const bf16x8*)(WqTL + ch * 8192 + (w * 64 + 16 * j + r16) * 32 + ko);
#pragma unroll
        for (int i = 0; i < 4; i++)
#pragma unroll
            for (int j = 0; j < 4; j++)
                accy[i][j] = MFMA(akv[i], bq[j], accy[i][j]);
    }
#pragma unroll
    for (int i = 0; i < 4; i++)
#pragma unroll
        for (int j = 0; j < 4; j++) {
            const int c = w * 64 + 16 * j + r16;
            const int e0 = 16 * i + quad * 4;
            union { u16x4 v; u16 s[4]; } pk;
#pragma unroll
            for (int rr = 0; rr < 4; rr++) pk.s[rr] = f2b(accy[i][j][rr]);
            *(u16x4*)(Zt + ((long long)(b * 256 + c)) * 512 + h * 64 + e0) = pk.v;
        }
}

// ---------------------------------------------------------------------------
// gemm_bt (proven, r2): C[m,n] = sum_k A[m,k]*Bm[n,k] (+bias[n]); bf16 A,B.
// ---------------------------------------------------------------------------
template <typename CT>
__global__ __launch_bounds__(256) void gemm_bt(
    const u16* __restrict__ A, const u16* __restrict__ Bm,
    CT* __restrict__ C, const float* __restrict__ bias,
    int K, int lda, int ldc,
    long long aStride, long long bStride, long long cStride)
{
    __shared__ u16 As[128 * 32];
    __shared__ u16 Bs[128 * 32];

    const int bz = blockIdx.z;
    A  += (long long)bz * aStride;
    Bm += (long long)bz * bStride;
    C  += (long long)bz * cStride;

    const int m0 = blockIdx.x * 128;
    const int n0 = blockIdx.y * 128;
    const int t  = threadIdx.x;
    const int wv = t >> 6, l = t & 63;
    const int wy = wv >> 1, wx = wv & 1;
    const int r16  = l & 15;
    const int quad = l >> 4;
    const int srow = wv * 16 + (l >> 2);
    const int scol = (l & 3) * 8;

    f32x4 acc[4][4] = {};

    for (int kk = 0; kk < K; kk += 32) {
#pragma unroll
        for (int s = 0; s < 2; s++) {
            GLD(A + (long long)(m0 + s * 64 + srow) * lda + kk + scol,
                As + s * 2048 + wv * 512);
            GLD(Bm + (long long)(n0 + s * 64 + srow) * K + kk + scol,
                Bs + s * 2048 + wv * 512);
        }
        __syncthreads();

        bf16x8 a[4], b[4];
#pragma unroll
        for (int i = 0; i < 4; i++)
            a[i] = *(const bf16x8*)(As + (wy * 64 + 16 * i + r16) * 32 + quad * 8);
#pragma unroll
        for (int j = 0; j < 4; j++)
            b[j] = *(const bf16x8*)(Bs + (wx * 64 + 16 * j + r16) * 32 + quad * 8);
#pragma unroll
        for (int i = 0; i < 4; i++)
#pragma unroll
            for (int j = 0; j < 4; j++)
                acc[i][j] = MFMA(a[i], b[j], acc[i][j]);
        __syncthreads();
    }

#pragma unroll
    for (int j = 0; j < 4; j++) {
        const int col = n0 + wx * 64 + 16 * j + r16;
        const float bv = bias ? bias[col] : 0.0f;
#pragma unroll
        for (int i = 0; i < 4; i++) {
#pragma unroll
            for (int r = 0; r < 4; r++) {
                const int row = m0 + wy * 64 + 16 * i + quad * 4 + r;
                const float v = acc[i][j][r] + bv;
                if constexpr (sizeof(CT) == 2) C[(long long)row * ldc + col] = f2b(v);
                else                           C[(long long)row * ldc + col] = v;
            }
        }
    }
}

// ---------------------------------------------------------------------------
// gemm_out v3 (proven, r6): out[n,o] = sum_c u_b[n,c]*Ft[o,c] + bo[o].
// 1024 thr, 16 waves (4x4), 32x64 per wave, acc[2][4]. grid (128, 1, 4).
// ---------------------------------------------------------------------------
__global__ __launch_bounds__(1024) void gemm_out(
    const u16* __restrict__ Au, const u16* __restrict__ Ft,
    float* __restrict__ C, const float* __restrict__ bias)
{
    __shared__ u16 As[128 * 32];   // 8 KB
    __shared__ u16 Bs[256 * 32];   // 16 KB

    const int b = blockIdx.z;
    Au += (long long)b * NTOT * CC;
    const u16* Bm = Ft + (long long)b * 65536;
    C += (long long)b * NTOT * OUTC;

    const int m0 = blockIdx.x * 128;
    const int t  = threadIdx.x;
    const int wv = t >> 6, l = t & 63;
    const int wy = wv >> 2, wx = wv & 3;   // 4x4 wave grid, 32x64 each
    const int r16  = l & 15;
    const int quad = l >> 4;
    const int srow = t >> 2;               // staging row
    const int scol = (t & 3) * 8;          // staging col (8 bf16 = 16 B)

    f32x4 acc[2][4] = {};

    for (int kk = 0; kk < 256; kk += 32) {
        // B: 256x32 staged by all 1024 thr (1 GLD, dest byte = 16*t: linear)
        GLD(Bm + (long long)srow * 256 + kk + scol, Bs + srow * 32 + scol);
        // A: 128x32 staged by waves 0..7 (t<512; wave-uniform branch)
        if (t < 512)
            GLD(Au + (long long)(m0 + srow) * CC + kk + scol, As + srow * 32 + scol);
        __syncthreads();

        bf16x8 a[2], bb[4];
#pragma unroll
        for (int i = 0; i < 2; i++)
            a[i] = *(const bf16x8*)(As + (wy * 32 + 16 * i + r16) * 32 + quad * 8);
#pragma unroll
        for (int j = 0; j < 4; j++)
            bb[j] = *(const bf16x8*)(Bs + (wx * 64 + 16 * j + r16) * 32 + quad * 8);
#pragma unroll
        for (int i = 0; i < 2; i++)
#pragma unroll
            for (int j = 0; j < 4; j++)
                acc[i][j] = MFMA(a[i], bb[j], acc[i][j]);
        __syncthreads();
    }

#pragma unroll
    for (int j = 0; j < 4; j++) {
        const int col = wx * 64 + 16 * j + r16;
        const float bv = bias[col];
#pragma unroll
        for (int i = 0; i < 2; i++) {
#pragma unroll
            for (int r = 0; r < 4; r++) {
                const int row = m0 + wy * 32 + 16 * i + quad * 4 + r;
                C[(long long)row * OUTC + col] = acc[i][j][r] + bv;
            }
        }
    }
}

// ---------------------------------------------------------------------------
extern "C" void kernel_launch(void* const* d_in, const int* in_sizes, int n_in,
                              void* d_out, int out_size, void* d_ws, size_t ws_size,
                              hipStream_t stream)
{
    const float* u_src = (const float*)d_in[0];
    // d_in[1] = pos_src (unused)
    const float* Wq = (const float*)d_in[2];
    const float* Wk = (const float*)d_in[3];
    const float* Wv = (const float*)d_in[4];
    const float* Wo = (const float*)d_in[5];
    const float* bo = (const float*)d_in[6];
    float* out = (float*)d_out;

    char* ws = (char*)d_ws;
    size_t off = 0;
    float* Gp  = (float*)(ws + off); off += 67108864;  // [256][256][256] f32 partials
    float* suP = (float*)(ws + off); off += 262144;    // [256][256] f32
    u16*  Gb   = (u16*)(ws + off);  off += 524288;     // [4][256][256] bf16
    u16*  Wq_b = (u16*)(ws + off);  off += 262144;
    u16*  Wk_b = (u16*)(ws + off);  off += 262144;     // adjacent to Wv_b -> stacked [1024][256]
    u16*  Wv_b = (u16*)(ws + off);  off += 262144;
    u16*  Wo_b = (u16*)(ws + off);  off += 262144;     // [256][512] bf16
    float* su  = (float*)(ws + off); off += 4096;      // [4][256] f32
    u16*  Zt   = (u16*)(ws + off);  off += 1048576;    // [4][256][512] bf16
    u16*  Ft   = (u16*)(ws + off);  off += 524288;     // [4][256][256] bf16
    u16*  P2   = (u16*)(ws + off);  off += 2097152;    // [4][1024][256] bf16 ([Wk;Wv] x G)
    u16*  u_b  = (u16*)(ws + off);  off += 33554432;   // [4][16384][256] bf16 (side product)

    const dim3 blk(256);

    // weights -> bf16
    wcvt<<<dim3(64, 1, 4), blk, 0, stream>>>(Wq, Wk, Wv, Wo, Wq_b, Wk_b, Wv_b, Wo_b);

    // G partials from f32 u (cvt+transpose in staging) + su partials + u_b emit
    ggemm<<<dim3(BB * 64), dim3(512), 0, stream>>>(u_src, Gp, suP, u_b);
    gred<<<dim3(64, BB), blk, 0, stream>>>(Gp, suP, Gb, su);

    // P2[b] = [Wk;Wv]_stacked (1024x256) x G_b (G symmetric -> B^T form exact)
    gemm_bt<u16><<<dim3(8, 2, BB), blk, 0, stream>>>(
        Wk_b, Gb, P2, nullptr, 256, 256, 256, 0, 65536, 262144);

    // stats/S/kv/Zt (short serial tail)
    skvz<<<dim3(BB * HH), blk, 0, stream>>>(P2, su, Wk_b, Wv_b, Wq_b, Zt);

    // Ft[b] = Wo Zt_b^T : [256x512]x[512x256]
    gemm_bt<u16><<<dim3(2, 2, BB), blk, 0, stream>>>(
        Wo_b, Zt, Ft, nullptr, 512, 512, 256, 0, 131072, 65536);

    // out = u_b Ft^T + bo (bf16 A via GLD, 16-wave low-acc block)
    gemm_out<<<dim3(128, 1, BB), dim3(1024), 0, stream>>>(u_b, Ft, out, bo);
}

// Round 8
// 204.625 us; speedup vs baseline: 1.1357x; 1.0284x over previous
//
#include <hip/hip_runtime.h>
#include <hip/hip_bf16.h>

// Problem constants (from reference setup_inputs)
#define BB    4
#define NTOT  16384
#define CC    256
#define HH    8
#define DD    64
#define HD    512
#define OUTC  256

typedef unsigned short u16;
typedef unsigned int u32;
typedef __attribute__((ext_vector_type(8))) short bf16x8;   // 8 bf16 in 4 VGPRs
typedef __attribute__((ext_vector_type(4))) float f32x4;
typedef __attribute__((ext_vector_type(4))) short u16x4;
typedef __attribute__((ext_vector_type(4))) u32 u32x4;

__device__ __forceinline__ float b2f(u16 u) {
    union { float f; u32 i; } x; x.i = ((u32)u) << 16; return x.f;
}
__device__ __forceinline__ u16 f2b(float f) {
    union { float f; u32 i; } x; x.f = f;
    u32 r = x.i + 0x7fffu + ((x.i >> 16) & 1u);   // round-to-nearest-even
    return (u16)(r >> 16);
}

#define GLD(gp, lp) __builtin_amdgcn_global_load_lds( \
    (const __attribute__((address_space(1))) void*)(gp), \
    (__attribute__((address_space(3))) void*)(lp), 16, 0, 0)

#define MFMA(a, b, c) __builtin_amdgcn_mfma_f32_16x16x32_bf16((a), (b), (c), 0, 0, 0)

// ---------------------------------------------------------------------------
// wcvt: 4 weight matrices (each 131072 f32) -> bf16. grid (64, 1, 4).
// ---------------------------------------------------------------------------
__global__ __launch_bounds__(256) void wcvt(
    const float* __restrict__ Wq, const float* __restrict__ Wk,
    const float* __restrict__ Wv, const float* __restrict__ Wo,
    u16* __restrict__ q, u16* __restrict__ k,
    u16* __restrict__ v, u16* __restrict__ o)
{
    const int z = blockIdx.z;
    const float* src = z == 0 ? Wq : z == 1 ? Wk : z == 2 ? Wv : Wo;
    u16* dst = z == 0 ? q : z == 1 ? k : z == 2 ? v : o;
    const int i = (blockIdx.x * 256 + threadIdx.x) * 8;
    const float4 a = *(const float4*)(src + i);
    const float4 b = *(const float4*)(src + i + 4);
    union { bf16x8 v; u16 s[8]; } w;
    w.s[0] = f2b(a.x); w.s[1] = f2b(a.y); w.s[2] = f2b(a.z); w.s[3] = f2b(a.w);
    w.s[4] = f2b(b.x); w.s[5] = f2b(b.y); w.s[6] = f2b(b.z); w.s[7] = f2b(b.w);
    *(bf16x8*)(dst + i) = w.v;
}

// ---------------------------------------------------------------------------
// ggemm v8: 512-n chunks (32/batch) -> Gp HALVED to 33.5 MB; 64-n slabs per
// iter -> 8 float4 (128 B) in flight per thread (2x outstanding bytes,
// Little's-law fix); acc[4][4] (64 AGPR). Block = 128-row half x 256 cols
// of a chunk's G-tile; pair blocks z <-> z^8 share the chunk -> SAME XCD ->
// twin's u-read hits L2. Staging/swizzle = proven v4 pattern. Only half-0
// emits u_b + suP. grid (256), 512 thr, Ts 37.1 KB.
// ---------------------------------------------------------------------------
__global__ __launch_bounds__(512) void ggemm(
    const float* __restrict__ u, float* __restrict__ Gp, float* __restrict__ suP,
    u16* __restrict__ u_b)
{
    __shared__ u32 Ts[32 * 290];   // 37.1 KB
    const int z = blockIdx.x;
    const int half = (z >> 3) & 1;               // row-half of the G-tile
    const int cg = ((z >> 4) << 3) | (z & 7);    // chunk 0..127 (z and z^8 pair)
    const int b = cg >> 5, ck = cg & 31;
    const float* base = u + (long long)b * NTOT * CC + (long long)ck * 512 * CC;
    u16* ub_base = u_b + (long long)b * NTOT * CC + (long long)ck * 512 * CC;
    const int t = threadIdx.x, w = t >> 6, l = t & 63;
    const int wy = w >> 2, wx = w & 3;           // 2x4 wave grid over 128x256
    const int r16 = l & 15, quad = l >> 4;
    const int sp = t >> 5;          // n-pair 0..15 (also stages pair sp+16)
    const int sq = t & 31;          // c-octet 0..31

    // column swizzle: col c -> 9*(c>>3) + (c&7); +18 per 16 cols
    const int csa0 = 9 * ((half * 128 + wy * 64 + r16) >> 3) + (r16 & 7);  // +18*i
    const int csb0 = 9 * ((wx * 64 + r16) >> 3) + (r16 & 7);               // +18*j

    f32x4 acc[4][4] = {};
    float su8[8] = {};

    float4 a0, a1, b0, b1, c0, c1, d0, d1;
    {   // rows 2sp, 2sp+1, 32+2sp, 33+2sp of slab 0
        const float* s1 = base + (long long)(2 * sp) * CC + sq * 8;
        const float* s2 = s1 + 32 * CC;
        a0 = *(const float4*)s1;        a1 = *(const float4*)(s1 + 4);
        b0 = *(const float4*)(s1 + CC); b1 = *(const float4*)(s1 + CC + 4);
        c0 = *(const float4*)s2;        c1 = *(const float4*)(s2 + 4);
        d0 = *(const float4*)(s2 + CC); d1 = *(const float4*)(s2 + CC + 4);
    }

    for (int it = 0; it < 8; it++) {
        __syncthreads();   // prev iter's frag reads complete (no-op first)
        {   // cvt 4 rows, su8 reg-accum, u_b emit (half0), pair-pack scatter
            union { bf16x8 v; u16 q[8]; } ra, rb, rc, rd;
            ra.q[0] = f2b(a0.x); ra.q[1] = f2b(a0.y); ra.q[2] = f2b(a0.z); ra.q[3] = f2b(a0.w);
            ra.q[4] = f2b(a1.x); ra.q[5] = f2b(a1.y); ra.q[6] = f2b(a1.z); ra.q[7] = f2b(a1.w);
            rb.q[0] = f2b(b0.x); rb.q[1] = f2b(b0.y); rb.q[2] = f2b(b0.z); rb.q[3] = f2b(b0.w);
            rb.q[4] = f2b(b1.x); rb.q[5] = f2b(b1.y); rb.q[6] = f2b(b1.z); rb.q[7] = f2b(b1.w);
            rc.q[0] = f2b(c0.x); rc.q[1] = f2b(c0.y); rc.q[2] = f2b(c0.z); rc.q[3] = f2b(c0.w);
            rc.q[4] = f2b(c1.x); rc.q[5] = f2b(c1.y); rc.q[6] = f2b(c1.z); rc.q[7] = f2b(c1.w);
            rd.q[0] = f2b(d0.x); rd.q[1] = f2b(d0.y); rd.q[2] = f2b(d0.z); rd.q[3] = f2b(d0.w);
            rd.q[4] = f2b(d1.x); rd.q[5] = f2b(d1.y); rd.q[6] = f2b(d1.z); rd.q[7] = f2b(d1.w);
            if (half == 0) {
#pragma unroll
                for (int k = 0; k < 8; k++)
                    su8[k] += (b2f(ra.q[k]) + b2f(rb.q[k])) + (b2f(rc.q[k]) + b2f(rd.q[k]));
                u16* ub = ub_base + (long long)(it * 64 + 2 * sp) * CC + sq * 8;
                *(bf16x8*)ub = ra.v;
                *(bf16x8*)(ub + CC) = rb.v;
                *(bf16x8*)(ub + 32 * CC) = rc.v;
                *(bf16x8*)(ub + 33 * CC) = rd.v;
            }
            u32* dst1 = Ts + sp * 290 + 9 * sq;
            u32* dst2 = Ts + (sp + 16) * 290 + 9 * sq;
#pragma unroll
            for (int k = 0; k < 8; k++) {
                dst1[k] = (u32)ra.q[k] | ((u32)rb.q[k] << 16);
                dst2[k] = (u32)rc.q[k] | ((u32)rd.q[k] << 16);
            }
        }
        if (it < 7) {   // prefetch next 64-n slab (8 float4 = 128 B in flight)
            const float* s1 = base + (long long)((it + 1) * 64 + 2 * sp) * CC + sq * 8;
            const float* s2 = s1 + 32 * CC;
            a0 = *(const float4*)s1;        a1 = *(const float4*)(s1 + 4);
            b0 = *(const float4*)(s1 + CC); b1 = *(const float4*)(s1 + CC + 4);
            c0 = *(const float4*)s2;        c1 = *(const float4*)(s2 + 4);
            d0 = *(const float4*)(s2 + CC); d1 = *(const float4*)(s2 + CC + 4);
        }
        __syncthreads();

#pragma unroll
        for (int kb = 0; kb < 2; kb++) {   // two K=32 sub-blocks of the slab
            const int pr0 = (kb * 16 + 4 * quad) * 290;
            bf16x8 a[4], bb[4];
#pragma unroll
            for (int i = 0; i < 4; i++) {
                const int cs = pr0 + csa0 + 18 * i;
                union { u32x4 u4; bf16x8 h; } f;
                f.u4[0] = Ts[cs];       f.u4[1] = Ts[290 + cs];
                f.u4[2] = Ts[580 + cs]; f.u4[3] = Ts[870 + cs];
                a[i] = f.h;
            }
#pragma unroll
            for (int j = 0; j < 4; j++) {
                const int cs = pr0 + csb0 + 18 * j;
                union { u32x4 u4; bf16x8 h; } f;
                f.u4[0] = Ts[cs];       f.u4[1] = Ts[290 + cs];
                f.u4[2] = Ts[580 + cs]; f.u4[3] = Ts[870 + cs];
                bb[j] = f.h;
            }
#pragma unroll
            for (int i = 0; i < 4; i++)
#pragma unroll
                for (int j = 0; j < 4; j++)
                    acc[i][j] = MFMA(a[i], bb[j], acc[i][j]);
        }
    }

    float* Cp = Gp + (long long)cg * 65536;
#pragma unroll
    for (int i = 0; i < 4; i++)
#pragma unroll
        for (int j = 0; j < 4; j++)
#pragma unroll
            for (int rr = 0; rr < 4; rr++)
                Cp[(half * 128 + wy * 64 + 16 * i + quad * 4 + rr) * 256
                   + wx * 64 + 16 * j + r16] = acc[i][j][rr];

    if (half == 0) {   // su reduce via Ts scratch (block-uniform branch)
        __syncthreads();
        float* S = (float*)Ts;   // [16][264] f32 = 16.9 KB < 37.1 KB
#pragma unroll
        for (int k = 0; k < 8; k++) S[sp * 264 + sq * 8 + k] = su8[k];
        __syncthreads();
        if (t < 256) {
            float s = 0.f;
#pragma unroll
            for (int p = 0; p < 16; p++) s += S[p * 264 + t];
            suP[cg * 256 + t] = s;
        }
    }
}

// ---------------------------------------------------------------------------
// gred: Gb[b][i][j] = bf16(sum_{ck<32} Gp), f32x4 per thread (4 cols).
// grid (64, 4), 256 thr; block x==0 also reduces suP -> su.
// ---------------------------------------------------------------------------
__global__ __launch_bounds__(256) void gred(
    const float* __restrict__ Gp, const float* __restrict__ suP,
    u16* __restrict__ Gb, float* __restrict__ su)
{
    const int b = blockIdx.y, t = threadIdx.x;
    const int row = blockIdx.x * 4 + (t >> 6);
    const int col = (t & 63) * 4;
    const float* p = Gp + (long long)(b * 32) * 65536 + row * 256 + col;
    f32x4 s = {};
#pragma unroll
    for (int ck = 0; ck < 32; ck++) {
        f32x4 v = *(const f32x4*)(p + (long long)ck * 65536);
        s[0] += v[0]; s[1] += v[1]; s[2] += v[2]; s[3] += v[3];
    }
    union { u16x4 v; u16 q[4]; } pk;
#pragma unroll
    for (int k = 0; k < 4; k++) pk.q[k] = f2b(s[k]);
    *(u16x4*)(Gb + (long long)b * 65536 + row * 256 + col) = pk.v;

    if (blockIdx.x == 0) {
        float s2 = 0.f;
#pragma unroll
        for (int ck = 0; ck < 32; ck++) s2 += suP[(b * 32 + ck) * 256 + t];
        su[b * 256 + t] = s2;
    }
}

// ---------------------------------------------------------------------------
// skvz: serial tail per (b,h). Inputs: P2 = [Wk;Wv]_stacked x G (bf16), su.
// stats via direct row-dots; S = Pk Wv^T (frags from global); kv -> kvT LDS;
// WqT staging + Y-phase. grid (32), 256 thr.
// ---------------------------------------------------------------------------
__global__ __launch_bounds__(256) void skvz(
    const u16* __restrict__ P2, const float* __restrict__ su,
    const u16* __restrict__ Wk_b, const u16* __restrict__ Wv_b,
    const u16* __restrict__ Wq_b, u16* __restrict__ Zt)
{
    __shared__ u16 pool[20480];   // kvTL 8KB + WqTL 32KB
    __shared__ float mkL[64], rkL[64], mvL[64], rvL[64];

    const int bx = blockIdx.x, b = bx >> 3, h = bx & 7;
    const int t = threadIdx.x, w = t >> 6, l = t & 63;
    const int r16 = l & 15, quad = l >> 4;

    const u16* WkH = Wk_b + (h * 64) * 256;
    const u16* WvH = Wv_b + (h * 64) * 256;
    const u16* PkH = P2 + (long long)b * 262144 + (h * 64) * 256;
    const u16* PvH = P2 + (long long)b * 262144 + (512 + h * 64) * 256;

    // ---- stats: 2 threads per row (128 rows: 64 k + 64 v) ----
    {
        const int row = t >> 1, half = t & 1;
        const u16* Prow = (row < 64 ? PkH + row * 256 : PvH + (row - 64) * 256) + half * 128;
        const u16* Wrow = (row < 64 ? WkH + row * 256 : WvH + (row - 64) * 256) + half * 128;
        const float* suB = su + b * 256 + half * 128;
        float e2 = 0.f, m = 0.f;
#pragma unroll
        for (int c8 = 0; c8 < 16; c8++) {
            bf16x8 pw = *(const bf16x8*)(Prow + c8 * 8);
            bf16x8 ww = *(const bf16x8*)(Wrow + c8 * 8);
#pragma unroll
            for (int k = 0; k < 8; k++) {
                const float wv_ = b2f((u16)ww[k]);
                e2 += b2f((u16)pw[k]) * wv_;
                m  += wv_ * suB[c8 * 8 + k];
            }
        }
        e2 += __shfl_xor(e2, 1);
        m  += __shfl_xor(m, 1);
        if (half == 0) {
            m *= (1.0f / NTOT);
            const float r = rsqrtf(e2 * (1.0f / NTOT) - m * m + 1e-5f);
            if (row < 64) { mkL[row] = m; rkL[row] = r; }
            else          { mvL[row - 64] = m; rvL[row - 64] = r; }
        }
    }
    __syncthreads();

    // ---- S-phase: S[d,e] = sum_c Pk[d,c] Wv[e,c]; frags from global ----
    const int mh = (w >> 1) * 32, nh = (w & 1) * 32;
    float mkR[2][4], rkR[2][4], mvR[2], rvR[2];
#pragma unroll
    for (int i = 0; i < 2; i++)
#pragma unroll
        for (int rr = 0; rr < 4; rr++) {
            mkR[i][rr] = mkL[mh + 16 * i + quad * 4 + rr];
            rkR[i][rr] = rkL[mh + 16 * i + quad * 4 + rr];
        }
#pragma unroll
    for (int j = 0; j < 2; j++) {
        mvR[j] = mvL[nh + 16 * j + r16];
        rvR[j] = rvL[nh + 16 * j + r16];
    }

    f32x4 accs[2][2] = {};
    for (int ch = 0; ch < 8; ch++) {
        const int ko = quad * 8;
        bf16x8 ap[2], bv[2];
#pragma unroll
        for (int i = 0; i < 2; i++)
            ap[i] = *(const bf16x8*)(PkH + (mh + 16 * i + r16) * 256 + ch * 32 + ko);
#pragma unroll
        for (int j = 0; j < 2; j++)
            bv[j] = *(const bf16x8*)(WvH + (nh + 16 * j + r16) * 256 + ch * 32 + ko);
#pragma unroll
        for (int i = 0; i < 2; i++)
#pragma unroll
            for (int j = 0; j < 2; j++)
                accs[i][j] = MFMA(ap[i], bv[j], accs[i][j]);
    }

    // ---- kv -> kvTL; WqTL ----
    u16* kvTL = pool;            // 8 KB
    u16* WqTL = pool + 4096;     // 32 KB
#pragma unroll
    for (int i = 0; i < 2; i++)
#pragma unroll
        for (int j = 0; j < 2; j++)
#pragma unroll
            for (int rr = 0; rr < 4; rr++) {
                const int d = mh + 16 * i + quad * 4 + rr;
                const int e = nh + 16 * j + r16;
                const float kv = rkR[i][rr] * rvR[j] *
                    (accs[i][j][rr] * (1.0f / NTOT) - mkR[i][rr] * mvR[j]);
                kvTL[(d >> 5) * 2048 + e * 32 + (d & 31)] = f2b(kv);
            }
    {
        const int d = t >> 2, q = t & 3;
        const u16* Wrow = Wq_b + (h * 64 + d) * 256 + q * 64;
#pragma unroll
        for (int s = 0; s < 8; s++) {
            bf16x8 raw = *(const bf16x8*)(Wrow + s * 8);
#pragma unroll
            for (int k = 0; k < 8; k++) {
                const int c = q * 64 + s * 8 + k;
                WqTL[(d >> 5) * 8192 + c * 32 + (d & 31)] = (u16)raw[k];
            }
        }
    }
    __syncthreads();

    // ---- Y-phase ----
    f32x4 accy[4][4] = {};
#pragma unroll
    for (int ch = 0; ch < 2; ch++) {
        const int ko = quad * 8;
        bf16x8 akv[4], bq[4];
#pragma unroll
        for (int i = 0; i < 4; i++)
            akv[i] = *(const bf16x8*)(kvTL + ch * 2048 + (16 * i + r16) * 32 + ko);
#pragma unroll
        for (int j = 0; j < 4; j++)
            bq[j] = *(const bf16x8*)(WqTL + ch * 8192 + (w * 64 + 16 * j + r16) * 32 + ko);
#pragma unroll
        for (int i = 0; i < 4; i++)
#pragma unroll
            for (int j = 0; j < 4; j++)
                accy[i][j] = MFMA(akv[i], bq[j], accy[i][j]);
    }
#pragma unroll
    for (int i = 0; i < 4; i++)
#pragma unroll
        for (int j = 0; j < 4; j++) {
            const int c = w * 64 + 16 * j + r16;
            const int e0 = 16 * i + quad * 4;
            union { u16x4 v; u16 s[4]; } pk;
#pragma unroll
            for (int rr = 0; rr < 4; rr++) pk.s[rr] = f2b(accy[i][j][rr]);
            *(u16x4*)(Zt + ((long long)(b * 256 + c)) * 512 + h * 64 + e0) = pk.v;
        }
}

// ---------------------------------------------------------------------------
// gemm_bt (proven, r2): C[m,n] = sum_k A[m,k]*Bm[n,k] (+bias[n]); bf16 A,B.
// ---------------------------------------------------------------------------
template <typename CT>
__global__ __launch_bounds__(256) void gemm_bt(
    const u16* __restrict__ A, const u16* __restrict__ Bm,
    CT* __restrict__ C, const float* __restrict__ bias,
    int K, int lda, int ldc,
    long long aStride, long long bStride, long long cStride)
{
    __shared__ u16 As[128 * 32];
    __shared__ u16 Bs[128 * 32];

    const int bz = blockIdx.z;
    A  += (long long)bz * aStride;
    Bm += (long long)bz * bStride;
    C  += (long long)bz * cStride;

    const int m0 = blockIdx.x * 128;
    const int n0 = blockIdx.y * 128;
    const int t  = threadIdx.x;
    const int wv = t >> 6, l = t & 63;
    const int wy = wv >> 1, wx = wv & 1;
    const int r16  = l & 15;
    const int quad = l >> 4;
    const int srow = wv * 16 + (l >> 2);
    const int scol = (l & 3) * 8;

    f32x4 acc[4][4] = {};

    for (int kk = 0; kk < K; kk += 32) {
#pragma unroll
        for (int s = 0; s < 2; s++) {
            GLD(A + (long long)(m0 + s * 64 + srow) * lda + kk + scol,
                As + s * 2048 + wv * 512);
            GLD(Bm + (long long)(n0 + s * 64 + srow) * K + kk + scol,
                Bs + s * 2048 + wv * 512);
        }
        __syncthreads();

        bf16x8 a[4], b[4];
#pragma unroll
        for (int i = 0; i < 4; i++)
            a[i] = *(const bf16x8*)(As + (wy * 64 + 16 * i + r16) * 32 + quad * 8);
#pragma unroll
        for (int j = 0; j < 4; j++)
            b[j] = *(const bf16x8*)(Bs + (wx * 64 + 16 * j + r16) * 32 + quad * 8);
#pragma unroll
        for (int i = 0; i < 4; i++)
#pragma unroll
            for (int j = 0; j < 4; j++)
                acc[i][j] = MFMA(a[i], b[j], acc[i][j]);
        __syncthreads();
    }

#pragma unroll
    for (int j = 0; j < 4; j++) {
        const int col = n0 + wx * 64 + 16 * j + r16;
        const float bv = bias ? bias[col] : 0.0f;
#pragma unroll
        for (int i = 0; i < 4; i++) {
#pragma unroll
            for (int r = 0; r < 4; r++) {
                const int row = m0 + wy * 64 + 16 * i + quad * 4 + r;
                const float v = acc[i][j][r] + bv;
                if constexpr (sizeof(CT) == 2) C[(long long)row * ldc + col] = f2b(v);
                else                           C[(long long)row * ldc + col] = v;
            }
        }
    }
}

// ---------------------------------------------------------------------------
// gemm_out v3 (proven, r6): out[n,o] = sum_c u_b[n,c]*Ft[o,c] + bo[o].
// 1024 thr, 16 waves (4x4), 32x64 per wave, acc[2][4]. grid (128, 1, 4).
// ---------------------------------------------------------------------------
__global__ __launch_bounds__(1024) void gemm_out(
    const u16* __restrict__ Au, const u16* __restrict__ Ft,
    float* __restrict__ C, const float* __restrict__ bias)
{
    __shared__ u16 As[128 * 32];   // 8 KB
    __shared__ u16 Bs[256 * 32];   // 16 KB

    const int b = blockIdx.z;
    Au += (long long)b * NTOT * CC;
    const u16* Bm = Ft + (long long)b * 65536;
    C += (long long)b * NTOT * OUTC;

    const int m0 = blockIdx.x * 128;
    const int t  = threadIdx.x;
    const int wv = t >> 6, l = t & 63;
    const int wy = wv >> 2, wx = wv & 3;   // 4x4 wave grid, 32x64 each
    const int r16  = l & 15;
    const int quad = l >> 4;
    const int srow = t >> 2;               // staging row
    const int scol = (t & 3) * 8;          // staging col (8 bf16 = 16 B)

    f32x4 acc[2][4] = {};

    for (int kk = 0; kk < 256; kk += 32) {
        // B: 256x32 staged by all 1024 thr (1 GLD, dest byte = 16*t: linear)
        GLD(Bm + (long long)srow * 256 + kk + scol, Bs + srow * 32 + scol);
        // A: 128x32 staged by waves 0..7 (t<512; wave-uniform branch)
        if (t < 512)
            GLD(Au + (long long)(m0 + srow) * CC + kk + scol, As + srow * 32 + scol);
        __syncthreads();

        bf16x8 a[2], bb[4];
#pragma unroll
        for (int i = 0; i < 2; i++)
            a[i] = *(const bf16x8*)(As + (wy * 32 + 16 * i + r16) * 32 + quad * 8);
#pragma unroll
        for (int j = 0; j < 4; j++)
            bb[j] = *(const bf16x8*)(Bs + (wx * 64 + 16 * j + r16) * 32 + quad * 8);
#pragma unroll
        for (int i = 0; i < 2; i++)
#pragma unroll
            for (int j = 0; j < 4; j++)
                acc[i][j] = MFMA(a[i], bb[j], acc[i][j]);
        __syncthreads();
    }

#pragma unroll
    for (int j = 0; j < 4; j++) {
        const int col = wx * 64 + 16 * j + r16;
        const float bv = bias[col];
#pragma unroll
        for (int i = 0; i < 2; i++) {
#pragma unroll
            for (int r = 0; r < 4; r++) {
                const int row = m0 + wy * 32 + 16 * i + quad * 4 + r;
                C[(long long)row * OUTC + col] = acc[i][j][r] + bv;
            }
        }
    }
}

// ---------------------------------------------------------------------------
extern "C" void kernel_launch(void* const* d_in, const int* in_sizes, int n_in,
                              void* d_out, int out_size, void* d_ws, size_t ws_size,
                              hipStream_t stream)
{
    const float* u_src = (const float*)d_in[0];
    // d_in[1] = pos_src (unused)
    const float* Wq = (const float*)d_in[2];
    const float* Wk = (const float*)d_in[3];
    const float* Wv = (const float*)d_in[4];
    const float* Wo = (const float*)d_in[5];
    const float* bo = (const float*)d_in[6];
    float* out = (float*)d_out;

    char* ws = (char*)d_ws;
    size_t off = 0;
    float* Gp  = (float*)(ws + off); off += 33554432;  // [128][256][256] f32 partials (halved)
    float* suP = (float*)(ws + off); off += 131072;    // [128][256] f32
    u16*  Gb   = (u16*)(ws + off);  off += 524288;     // [4][256][256] bf16
    u16*  Wq_b = (u16*)(ws + off);  off += 262144;
    u16*  Wk_b = (u16*)(ws + off);  off += 262144;     // adjacent to Wv_b -> stacked [1024][256]
    u16*  Wv_b = (u16*)(ws + off);  off += 262144;
    u16*  Wo_b = (u16*)(ws + off);  off += 262144;     // [256][512] bf16
    float* su  = (float*)(ws + off); off += 4096;      // [4][256] f32
    u16*  Zt   = (u16*)(ws + off);  off += 1048576;    // [4][256][512] bf16
    u16*  Ft   = (u16*)(ws + off);  off += 524288;     // [4][256][256] bf16
    u16*  P2   = (u16*)(ws + off);  off += 2097152;    // [4][1024][256] bf16 ([Wk;Wv] x G)
    u16*  u_b  = (u16*)(ws + off);  off += 33554432;   // [4][16384][256] bf16 (side product)

    const dim3 blk(256);

    // weights -> bf16
    wcvt<<<dim3(64, 1, 4), blk, 0, stream>>>(Wq, Wk, Wv, Wo, Wq_b, Wk_b, Wv_b, Wo_b);

    // G partials (512-n chunks, 2 row-half blocks each, XCD-paired) + su + u_b
    ggemm<<<dim3(256), dim3(512), 0, stream>>>(u_src, Gp, suP, u_b);
    gred<<<dim3(64, BB), blk, 0, stream>>>(Gp, suP, Gb, su);

    // P2[b] = [Wk;Wv]_stacked (1024x256) x G_b (G symmetric -> B^T form exact)
    gemm_bt<u16><<<dim3(8, 2, BB), blk, 0, stream>>>(
        Wk_b, Gb, P2, nullptr, 256, 256, 256, 0, 65536, 262144);

    // stats/S/kv/Zt (short serial tail)
    skvz<<<dim3(BB * HH), blk, 0, stream>>>(P2, su, Wk_b, Wv_b, Wq_b, Zt);

    // Ft[b] = Wo Zt_b^T : [256x512]x[512x256]
    gemm_bt<u16><<<dim3(2, 2, BB), blk, 0, stream>>>(
        Wo_b, Zt, Ft, nullptr, 512, 512, 256, 0, 131072, 65536);

    // out = u_b Ft^T + bo (bf16 A via GLD, 16-wave low-acc block)
    gemm_out<<<dim3(128, 1, BB), dim3(1024), 0, stream>>>(u_b, Ft, out, bo);
}

// Round 9
// 202.293 us; speedup vs baseline: 1.1488x; 1.0115x over previous
//
#include <hip/hip_runtime.h>
#include <hip/hip_bf16.h>

// Problem constants (from reference setup_inputs)
#define BB    4
#define NTOT  16384
#define CC    256
#define HH    8
#define DD    64
#define HD    512
#define OUTC  256

typedef unsigned short u16;
typedef unsigned int u32;
typedef __attribute__((ext_vector_type(8))) short bf16x8;   // 8 bf16 in 4 VGPRs
typedef __attribute__((ext_vector_type(4))) float f32x4;
typedef __attribute__((ext_vector_type(4))) short u16x4;
typedef __attribute__((ext_vector_type(4))) u32 u32x4;

__device__ __forceinline__ float b2f(u16 u) {
    union { float f; u32 i; } x; x.i = ((u32)u) << 16; return x.f;
}
__device__ __forceinline__ u16 f2b(float f) {
    union { float f; u32 i; } x; x.f = f;
    u32 r = x.i + 0x7fffu + ((x.i >> 16) & 1u);   // round-to-nearest-even
    return (u16)(r >> 16);
}

#define GLD(gp, lp) __builtin_amdgcn_global_load_lds( \
    (const __attribute__((address_space(1))) void*)(gp), \
    (__attribute__((address_space(3))) void*)(lp), 16, 0, 0)

#define MFMA(a, b, c) __builtin_amdgcn_mfma_f32_16x16x32_bf16((a), (b), (c), 0, 0, 0)

// ---------------------------------------------------------------------------
// wcvt: 4 weight matrices (each 131072 f32) -> bf16. grid (64, 1, 4).
// ---------------------------------------------------------------------------
__global__ __launch_bounds__(256) void wcvt(
    const float* __restrict__ Wq, const float* __restrict__ Wk,
    const float* __restrict__ Wv, const float* __restrict__ Wo,
    u16* __restrict__ q, u16* __restrict__ k,
    u16* __restrict__ v, u16* __restrict__ o)
{
    const int z = blockIdx.z;
    const float* src = z == 0 ? Wq : z == 1 ? Wk : z == 2 ? Wv : Wo;
    u16* dst = z == 0 ? q : z == 1 ? k : z == 2 ? v : o;
    const int i = (blockIdx.x * 256 + threadIdx.x) * 8;
    const float4 a = *(const float4*)(src + i);
    const float4 b = *(const float4*)(src + i + 4);
    union { bf16x8 v; u16 s[8]; } w;
    w.s[0] = f2b(a.x); w.s[1] = f2b(a.y); w.s[2] = f2b(a.z); w.s[3] = f2b(a.w);
    w.s[4] = f2b(b.x); w.s[5] = f2b(b.y); w.s[6] = f2b(b.z); w.s[7] = f2b(b.w);
    *(bf16x8*)(dst + i) = w.v;
}

// ---------------------------------------------------------------------------
// ggemm v9: v8 + DEPTH-2 register prefetch. Two prefetch sets pf[0]/pf[1]
// (compile-time indexed after full unroll); prologue issues slabs 0 and 1
// (16 float4 = 256 B/thread outstanding); iter it converts pf[it&1] then
// reissues that set for slab it+2 -> loads get ~2 iterations (>1000 cyc) to
// land, covering HBM latency (Little's-law fix #2). cvt/scatter/su8/u_b
// byte-identical to v8. grid (256), 512 thr, Ts 37.1 KB.
// ---------------------------------------------------------------------------
__global__ __launch_bounds__(512) void ggemm(
    const float* __restrict__ u, float* __restrict__ Gp, float* __restrict__ suP,
    u16* __restrict__ u_b)
{
    __shared__ u32 Ts[32 * 290];   // 37.1 KB
    const int z = blockIdx.x;
    const int half = (z >> 3) & 1;               // row-half of the G-tile
    const int cg = ((z >> 4) << 3) | (z & 7);    // chunk 0..127 (z and z^8 pair)
    const int b = cg >> 5, ck = cg & 31;
    const float* base = u + (long long)b * NTOT * CC + (long long)ck * 512 * CC;
    u16* ub_base = u_b + (long long)b * NTOT * CC + (long long)ck * 512 * CC;
    const int t = threadIdx.x, w = t >> 6, l = t & 63;
    const int wy = w >> 2, wx = w & 3;           // 2x4 wave grid over 128x256
    const int r16 = l & 15, quad = l >> 4;
    const int sp = t >> 5;          // n-pair 0..15 (also stages pair sp+16)
    const int sq = t & 31;          // c-octet 0..31

    // column swizzle: col c -> 9*(c>>3) + (c&7); +18 per 16 cols
    const int csa0 = 9 * ((half * 128 + wy * 64 + r16) >> 3) + (r16 & 7);  // +18*i
    const int csb0 = 9 * ((wx * 64 + r16) >> 3) + (r16 & 7);               // +18*j

    f32x4 acc[4][4] = {};
    float su8[8] = {};

    // pf[s][0..1]=row 2sp, [2..3]=row 2sp+1, [4..5]=row 32+2sp, [6..7]=row 33+2sp
    float4 pf[2][8];
#pragma unroll
    for (int s = 0; s < 2; s++) {   // prologue: slabs 0 and 1 in flight
        const float* s1 = base + (long long)(s * 64 + 2 * sp) * CC + sq * 8;
        const float* s2 = s1 + 32 * CC;
        pf[s][0] = *(const float4*)s1;        pf[s][1] = *(const float4*)(s1 + 4);
        pf[s][2] = *(const float4*)(s1 + CC); pf[s][3] = *(const float4*)(s1 + CC + 4);
        pf[s][4] = *(const float4*)s2;        pf[s][5] = *(const float4*)(s2 + 4);
        pf[s][6] = *(const float4*)(s2 + CC); pf[s][7] = *(const float4*)(s2 + CC + 4);
    }

#pragma unroll
    for (int it = 0; it < 8; it++) {
        const int ps = it & 1;      // compile-time after full unroll
        __syncthreads();   // prev iter's frag reads complete (no-op first)
        {   // cvt 4 rows, su8 reg-accum, u_b emit (half0), pair-pack scatter
            union { bf16x8 v; u16 q[8]; } ra, rb, rc, rd;
            ra.q[0] = f2b(pf[ps][0].x); ra.q[1] = f2b(pf[ps][0].y);
            ra.q[2] = f2b(pf[ps][0].z); ra.q[3] = f2b(pf[ps][0].w);
            ra.q[4] = f2b(pf[ps][1].x); ra.q[5] = f2b(pf[ps][1].y);
            ra.q[6] = f2b(pf[ps][1].z); ra.q[7] = f2b(pf[ps][1].w);
            rb.q[0] = f2b(pf[ps][2].x); rb.q[1] = f2b(pf[ps][2].y);
            rb.q[2] = f2b(pf[ps][2].z); rb.q[3] = f2b(pf[ps][2].w);
            rb.q[4] = f2b(pf[ps][3].x); rb.q[5] = f2b(pf[ps][3].y);
            rb.q[6] = f2b(pf[ps][3].z); rb.q[7] = f2b(pf[ps][3].w);
            rc.q[0] = f2b(pf[ps][4].x); rc.q[1] = f2b(pf[ps][4].y);
            rc.q[2] = f2b(pf[ps][4].z); rc.q[3] = f2b(pf[ps][4].w);
            rc.q[4] = f2b(pf[ps][5].x); rc.q[5] = f2b(pf[ps][5].y);
            rc.q[6] = f2b(pf[ps][5].z); rc.q[7] = f2b(pf[ps][5].w);
            rd.q[0] = f2b(pf[ps][6].x); rd.q[1] = f2b(pf[ps][6].y);
            rd.q[2] = f2b(pf[ps][6].z); rd.q[3] = f2b(pf[ps][6].w);
            rd.q[4] = f2b(pf[ps][7].x); rd.q[5] = f2b(pf[ps][7].y);
            rd.q[6] = f2b(pf[ps][7].z); rd.q[7] = f2b(pf[ps][7].w);
            if (half == 0) {
#pragma unroll
                for (int k = 0; k < 8; k++)
                    su8[k] += (b2f(ra.q[k]) + b2f(rb.q[k])) + (b2f(rc.q[k]) + b2f(rd.q[k]));
                u16* ub = ub_base + (long long)(it * 64 + 2 * sp) * CC + sq * 8;
                *(bf16x8*)ub = ra.v;
                *(bf16x8*)(ub + CC) = rb.v;
                *(bf16x8*)(ub + 32 * CC) = rc.v;
                *(bf16x8*)(ub + 33 * CC) = rd.v;
            }
            u32* dst1 = Ts + sp * 290 + 9 * sq;
            u32* dst2 = Ts + (sp + 16) * 290 + 9 * sq;
#pragma unroll
            for (int k = 0; k < 8; k++) {
                dst1[k] = (u32)ra.q[k] | ((u32)rb.q[k] << 16);
                dst2[k] = (u32)rc.q[k] | ((u32)rd.q[k] << 16);
            }
        }
        if (it < 6) {   // reissue consumed set for slab it+2 (2-iter cover)
            const float* s1 = base + (long long)((it + 2) * 64 + 2 * sp) * CC + sq * 8;
            const float* s2 = s1 + 32 * CC;
            pf[ps][0] = *(const float4*)s1;        pf[ps][1] = *(const float4*)(s1 + 4);
            pf[ps][2] = *(const float4*)(s1 + CC); pf[ps][3] = *(const float4*)(s1 + CC + 4);
            pf[ps][4] = *(const float4*)s2;        pf[ps][5] = *(const float4*)(s2 + 4);
            pf[ps][6] = *(const float4*)(s2 + CC); pf[ps][7] = *(const float4*)(s2 + CC + 4);
        }
        __syncthreads();

#pragma unroll
        for (int kb = 0; kb < 2; kb++) {   // two K=32 sub-blocks of the slab
            const int pr0 = (kb * 16 + 4 * quad) * 290;
            bf16x8 a[4], bb[4];
#pragma unroll
            for (int i = 0; i < 4; i++) {
                const int cs = pr0 + csa0 + 18 * i;
                union { u32x4 u4; bf16x8 h; } f;
                f.u4[0] = Ts[cs];       f.u4[1] = Ts[290 + cs];
                f.u4[2] = Ts[580 + cs]; f.u4[3] = Ts[870 + cs];
                a[i] = f.h;
            }
#pragma unroll
            for (int j = 0; j < 4; j++) {
                const int cs = pr0 + csb0 + 18 * j;
                union { u32x4 u4; bf16x8 h; } f;
                f.u4[0] = Ts[cs];       f.u4[1] = Ts[290 + cs];
                f.u4[2] = Ts[580 + cs]; f.u4[3] = Ts[870 + cs];
                bb[j] = f.h;
            }
#pragma unroll
            for (int i = 0; i < 4; i++)
#pragma unroll
                for (int j = 0; j < 4; j++)
                    acc[i][j] = MFMA(a[i], bb[j], acc[i][j]);
        }
    }

    float* Cp = Gp + (long long)cg * 65536;
#pragma unroll
    for (int i = 0; i < 4; i++)
#pragma unroll
        for (int j = 0; j < 4; j++)
#pragma unroll
            for (int rr = 0; rr < 4; rr++)
                Cp[(half * 128 + wy * 64 + 16 * i + quad * 4 + rr) * 256
                   + wx * 64 + 16 * j + r16] = acc[i][j][rr];

    if (half == 0) {   // su reduce via Ts scratch (block-uniform branch)
        __syncthreads();
        float* S = (float*)Ts;   // [16][264] f32 = 16.9 KB < 37.1 KB
#pragma unroll
        for (int k = 0; k < 8; k++) S[sp * 264 + sq * 8 + k] = su8[k];
        __syncthreads();
        if (t < 256) {
            float s = 0.f;
#pragma unroll
            for (int p = 0; p < 16; p++) s += S[p * 264 + t];
            suP[cg * 256 + t] = s;
        }
    }
}

// ---------------------------------------------------------------------------
// gred: Gb[b][i][j] = bf16(sum_{ck<32} Gp), f32x4 per thread (4 cols).
// grid (64, 4), 256 thr; block x==0 also reduces suP -> su.
// ---------------------------------------------------------------------------
__global__ __launch_bounds__(256) void gred(
    const float* __restrict__ Gp, const float* __restrict__ suP,
    u16* __restrict__ Gb, float* __restrict__ su)
{
    const int b = blockIdx.y, t = threadIdx.x;
    const int row = blockIdx.x * 4 + (t >> 6);
    const int col = (t & 63) * 4;
    const float* p = Gp + (long long)(b * 32) * 65536 + row * 256 + col;
    f32x4 s = {};
#pragma unroll
    for (int ck = 0; ck < 32; ck++) {
        f32x4 v = *(const f32x4*)(p + (long long)ck * 65536);
        s[0] += v[0]; s[1] += v[1]; s[2] += v[2]; s[3] += v[3];
    }
    union { u16x4 v; u16 q[4]; } pk;
#pragma unroll
    for (int k = 0; k < 4; k++) pk.q[k] = f2b(s[k]);
    *(u16x4*)(Gb + (long long)b * 65536 + row * 256 + col) = pk.v;

    if (blockIdx.x == 0) {
        float s2 = 0.f;
#pragma unroll
        for (int ck = 0; ck < 32; ck++) s2 += suP[(b * 32 + ck) * 256 + t];
        su[b * 256 + t] = s2;
    }
}

// ---------------------------------------------------------------------------
// skvz: serial tail per (b,h). Inputs: P2 = [Wk;Wv]_stacked x G (bf16), su.
// stats via direct row-dots; S = Pk Wv^T (frags from global); kv -> kvT LDS;
// WqT staging + Y-phase. grid (32), 256 thr.
// ---------------------------------------------------------------------------
__global__ __launch_bounds__(256) void skvz(
    const u16* __restrict__ P2, const float* __restrict__ su,
    const u16* __restrict__ Wk_b, const u16* __restrict__ Wv_b,
    const u16* __restrict__ Wq_b, u16* __restrict__ Zt)
{
    __shared__ u16 pool[20480];   // kvTL 8KB + WqTL 32KB
    __shared__ float mkL[64], rkL[64], mvL[64], rvL[64];

    const int bx = blockIdx.x, b = bx >> 3, h = bx & 7;
    const int t = threadIdx.x, w = t >> 6, l = t & 63;
    const int r16 = l & 15, quad = l >> 4;

    const u16* WkH = Wk_b + (h * 64) * 256;
    const u16* WvH = Wv_b + (h * 64) * 256;
    const u16* PkH = P2 + (long long)b * 262144 + (h * 64) * 256;
    const u16* PvH = P2 + (long long)b * 262144 + (512 + h * 64) * 256;

    // ---- stats: 2 threads per row (128 rows: 64 k + 64 v) ----
    {
        const int row = t >> 1, half = t & 1;
        const u16* Prow = (row < 64 ? PkH + row * 256 : PvH + (row - 64) * 256) + half * 128;
        const u16* Wrow = (row < 64 ? WkH + row * 256 : WvH + (row - 64) * 256) + half * 128;
        const float* suB = su + b * 256 + half * 128;
        float e2 = 0.f, m = 0.f;
#pragma unroll
        for (int c8 = 0; c8 < 16; c8++) {
            bf16x8 pw = *(const bf16x8*)(Prow + c8 * 8);
            bf16x8 ww = *(const bf16x8*)(Wrow + c8 * 8);
#pragma unroll
            for (int k = 0; k < 8; k++) {
                const float wv_ = b2f((u16)ww[k]);
                e2 += b2f((u16)pw[k]) * wv_;
                m  += wv_ * suB[c8 * 8 + k];
            }
        }
        e2 += __shfl_xor(e2, 1);
        m  += __shfl_xor(m, 1);
        if (half == 0) {
            m *= (1.0f / NTOT);
            const float r = rsqrtf(e2 * (1.0f / NTOT) - m * m + 1e-5f);
            if (row < 64) { mkL[row] = m; rkL[row] = r; }
            else          { mvL[row - 64] = m; rvL[row - 64] = r; }
        }
    }
    __syncthreads();

    // ---- S-phase: S[d,e] = sum_c Pk[d,c] Wv[e,c]; frags from global ----
    const int mh = (w >> 1) * 32, nh = (w & 1) * 32;
    float mkR[2][4], rkR[2][4], mvR[2], rvR[2];
#pragma unroll
    for (int i = 0; i < 2; i++)
#pragma unroll
        for (int rr = 0; rr < 4; rr++) {
            mkR[i][rr] = mkL[mh + 16 * i + quad * 4 + rr];
            rkR[i][rr] = rkL[mh + 16 * i + quad * 4 + rr];
        }
#pragma unroll
    for (int j = 0; j < 2; j++) {
        mvR[j] = mvL[nh + 16 * j + r16];
        rvR[j] = rvL[nh + 16 * j + r16];
    }

    f32x4 accs[2][2] = {};
    for (int ch = 0; ch < 8; ch++) {
        const int ko = quad * 8;
        bf16x8 ap[2], bv[2];
#pragma unroll
        for (int i = 0; i < 2; i++)
            ap[i] = *(const bf16x8*)(PkH + (mh + 16 * i + r16) * 256 + ch * 32 + ko);
#pragma unroll
        for (int j = 0; j < 2; j++)
            bv[j] = *(const bf16x8*)(WvH + (nh + 16 * j + r16) * 256 + ch * 32 + ko);
#pragma unroll
        for (int i = 0; i < 2; i++)
#pragma unroll
            for (int j = 0; j < 2; j++)
                accs[i][j] = MFMA(ap[i], bv[j], accs[i][j]);
    }

    // ---- kv -> kvTL; WqTL ----
    u16* kvTL = pool;            // 8 KB
    u16* WqTL = pool + 4096;     // 32 KB
#pragma unroll
    for (int i = 0; i < 2; i++)
#pragma unroll
        for (int j = 0; j < 2; j++)
#pragma unroll
            for (int rr = 0; rr < 4; rr++) {
                const int d = mh + 16 * i + quad * 4 + rr;
                const int e = nh + 16 * j + r16;
                const float kv = rkR[i][rr] * rvR[j] *
                    (accs[i][j][rr] * (1.0f / NTOT) - mkR[i][rr] * mvR[j]);
                kvTL[(d >> 5) * 2048 + e * 32 + (d & 31)] = f2b(kv);
            }
    {
        const int d = t >> 2, q = t & 3;
        const u16* Wrow = Wq_b + (h * 64 + d) * 256 + q * 64;
#pragma unroll
        for (int s = 0; s < 8; s++) {
            bf16x8 raw = *(const bf16x8*)(Wrow + s * 8);
#pragma unroll
            for (int k = 0; k < 8; k++) {
                const int c = q * 64 + s * 8 + k;
                WqTL[(d >> 5) * 8192 + c * 32 + (d & 31)] = (u16)raw[k];
            }
        }
    }
    __syncthreads();

    // ---- Y-phase ----
    f32x4 accy[4][4] = {};
#pragma unroll
    for (int ch = 0; ch < 2; ch++) {
        const int ko = quad * 8;
        bf16x8 akv[4], bq[4];
#pragma unroll
        for (int i = 0; i < 4; i++)
            akv[i] = *(const bf16x8*)(kvTL + ch * 2048 + (16 * i + r16) * 32 + ko);
#pragma unroll
        for (int j = 0; j < 4; j++)
            bq[j] = *(const bf16x8*)(WqTL + ch * 8192 + (w * 64 + 16 * j + r16) * 32 + ko);
#pragma unroll
        for (int i = 0; i < 4; i++)
#pragma unroll
            for (int j = 0; j < 4; j++)
                accy[i][j] = MFMA(akv[i], bq[j], accy[i][j]);
    }
#pragma unroll
    for (int i = 0; i < 4; i++)
#pragma unroll
        for (int j = 0; j < 4; j++) {
            const int c = w * 64 + 16 * j + r16;
            const int e0 = 16 * i + quad * 4;
            union { u16x4 v; u16 s[4]; } pk;
#pragma unroll
            for (int rr = 0; rr < 4; rr++) pk.s[rr] = f2b(accy[i][j][rr]);
            *(u16x4*)(Zt + ((long long)(b * 256 + c)) * 512 + h * 64 + e0) = pk.v;
        }
}

// ---------------------------------------------------------------------------
// gemm_bt (proven, r2): C[m,n] = sum_k A[m,k]*Bm[n,k] (+bias[n]); bf16 A,B.
// ---------------------------------------------------------------------------
template <typename CT>
__global__ __launch_bounds__(256) void gemm_bt(
    const u16* __restrict__ A, const u16* __restrict__ Bm,
    CT* __restrict__ C, const float* __restrict__ bias,
    int K, int lda, int ldc,
    long long aStride, long long bStride, long long cStride)
{
    __shared__ u16 As[128 * 32];
    __shared__ u16 Bs[128 * 32];

    const int bz = blockIdx.z;
    A  += (long long)bz * aStride;
    Bm += (long long)bz * bStride;
    C  += (long long)bz * cStride;

    const int m0 = blockIdx.x * 128;
    const int n0 = blockIdx.y * 128;
    const int t  = threadIdx.x;
    const int wv = t >> 6, l = t & 63;
    const int wy = wv >> 1, wx = wv & 1;
    const int r16  = l & 15;
    const int quad = l >> 4;
    const int srow = wv * 16 + (l >> 2);
    const int scol = (l & 3) * 8;

    f32x4 acc[4][4] = {};

    for (int kk = 0; kk < K; kk += 32) {
#pragma unroll
        for (int s = 0; s < 2; s++) {
            GLD(A + (long long)(m0 + s * 64 + srow) * lda + kk + scol,
                As + s * 2048 + wv * 512);
            GLD(Bm + (long long)(n0 + s * 64 + srow) * K + kk + scol,
                Bs + s * 2048 + wv * 512);
        }
        __syncthreads();

        bf16x8 a[4], b[4];
#pragma unroll
        for (int i = 0; i < 4; i++)
            a[i] = *(const bf16x8*)(As + (wy * 64 + 16 * i + r16) * 32 + quad * 8);
#pragma unroll
        for (int j = 0; j < 4; j++)
            b[j] = *(const bf16x8*)(Bs + (wx * 64 + 16 * j + r16) * 32 + quad * 8);
#pragma unroll
        for (int i = 0; i < 4; i++)
#pragma unroll
            for (int j = 0; j < 4; j++)
                acc[i][j] = MFMA(a[i], b[j], acc[i][j]);
        __syncthreads();
    }

#pragma unroll
    for (int j = 0; j < 4; j++) {
        const int col = n0 + wx * 64 + 16 * j + r16;
        const float bv = bias ? bias[col] : 0.0f;
#pragma unroll
        for (int i = 0; i < 4; i++) {
#pragma unroll
            for (int r = 0; r < 4; r++) {
                const int row = m0 + wy * 64 + 16 * i + quad * 4 + r;
                const float v = acc[i][j][r] + bv;
                if constexpr (sizeof(CT) == 2) C[(long long)row * ldc + col] = f2b(v);
                else                           C[(long long)row * ldc + col] = v;
            }
        }
    }
}

// ---------------------------------------------------------------------------
// gemm_out v3 (proven, r6): out[n,o] = sum_c u_b[n,c]*Ft[o,c] + bo[o].
// 1024 thr, 16 waves (4x4), 32x64 per wave, acc[2][4]. grid (128, 1, 4).
// ---------------------------------------------------------------------------
__global__ __launch_bounds__(1024) void gemm_out(
    const u16* __restrict__ Au, const u16* __restrict__ Ft,
    float* __restrict__ C, const float* __restrict__ bias)
{
    __shared__ u16 As[128 * 32];   // 8 KB
    __shared__ u16 Bs[256 * 32];   // 16 KB

    const int b = blockIdx.z;
    Au += (long long)b * NTOT * CC;
    const u16* Bm = Ft + (long long)b * 65536;
    C += (long long)b * NTOT * OUTC;

    const int m0 = blockIdx.x * 128;
    const int t  = threadIdx.x;
    const int wv = t >> 6, l = t & 63;
    const int wy = wv >> 2, wx = wv & 3;   // 4x4 wave grid, 32x64 each
    const int r16  = l & 15;
    const int quad = l >> 4;
    const int srow = t >> 2;               // staging row
    const int scol = (t & 3) * 8;          // staging col (8 bf16 = 16 B)

    f32x4 acc[2][4] = {};

    for (int kk = 0; kk < 256; kk += 32) {
        // B: 256x32 staged by all 1024 thr (1 GLD, dest byte = 16*t: linear)
        GLD(Bm + (long long)srow * 256 + kk + scol, Bs + srow * 32 + scol);
        // A: 128x32 staged by waves 0..7 (t<512; wave-uniform branch)
        if (t < 512)
            GLD(Au + (long long)(m0 + srow) * CC + kk + scol, As + srow * 32 + scol);
        __syncthreads();

        bf16x8 a[2], bb[4];
#pragma unroll
        for (int i = 0; i < 2; i++)
            a[i] = *(const bf16x8*)(As + (wy * 32 + 16 * i + r16) * 32 + quad * 8);
#pragma unroll
        for (int j = 0; j < 4; j++)
            bb[j] = *(const bf16x8*)(Bs + (wx * 64 + 16 * j + r16) * 32 + quad * 8);
#pragma unroll
        for (int i = 0; i < 2; i++)
#pragma unroll
            for (int j = 0; j < 4; j++)
                acc[i][j] = MFMA(a[i], bb[j], acc[i][j]);
        __syncthreads();
    }

#pragma unroll
    for (int j = 0; j < 4; j++) {
        const int col = wx * 64 + 16 * j + r16;
        const float bv = bias[col];
#pragma unroll
        for (int i = 0; i < 2; i++) {
#pragma unroll
            for (int r = 0; r < 4; r++) {
                const int row = m0 + wy * 32 + 16 * i + quad * 4 + r;
                C[(long long)row * OUTC + col] = acc[i][j][r] + bv;
            }
        }
    }
}

// ---------------------------------------------------------------------------
extern "C" void kernel_launch(void* const* d_in, const int* in_sizes, int n_in,
                              void* d_out, int out_size, void* d_ws, size_t ws_size,
                              hipStream_t stream)
{
    const float* u_src = (const float*)d_in[0];
    // d_in[1] = pos_src (unused)
    const float* Wq = (const float*)d_in[2];
    const float* Wk = (const float*)d_in[3];
    const float* Wv = (const float*)d_in[4];
    const float* Wo = (const float*)d_in[5];
    const float* bo = (const float*)d_in[6];
    float* out = (float*)d_out;

    char* ws = (char*)d_ws;
    size_t off = 0;
    float* Gp  = (float*)(ws + off); off += 33554432;  // [128][256][256] f32 partials
    float* suP = (float*)(ws + off); off += 131072;    // [128][256] f32
    u16*  Gb   = (u16*)(ws + off);  off += 524288;     // [4][256][256] bf16
    u16*  Wq_b = (u16*)(ws + off);  off += 262144;
    u16*  Wk_b = (u16*)(ws + off);  off += 262144;     // adjacent to Wv_b -> stacked [1024][256]
    u16*  Wv_b = (u16*)(ws + off);  off += 262144;
    u16*  Wo_b = (u16*)(ws + off);  off += 262144;     // [256][512] bf16
    float* su  = (float*)(ws + off); off += 4096;      // [4][256] f32
    u16*  Zt   = (u16*)(ws + off);  off += 1048576;    // [4][256][512] bf16
    u16*  Ft   = (u16*)(ws + off);  off += 524288;     // [4][256][256] bf16
    u16*  P2   = (u16*)(ws + off);  off += 2097152;    // [4][1024][256] bf16 ([Wk;Wv] x G)
    u16*  u_b  = (u16*)(ws + off);  off += 33554432;   // [4][16384][256] bf16 (side product)

    const dim3 blk(256);

    // weights -> bf16
    wcvt<<<dim3(64, 1, 4), blk, 0, stream>>>(Wq, Wk, Wv, Wo, Wq_b, Wk_b, Wv_b, Wo_b);

    // G partials (512-n chunks, 2 row-half blocks each, XCD-paired) + su + u_b
    ggemm<<<dim3(256), dim3(512), 0, stream>>>(u_src, Gp, suP, u_b);
    gred<<<dim3(64, BB), blk, 0, stream>>>(Gp, suP, Gb, su);

    // P2[b] = [Wk;Wv]_stacked (1024x256) x G_b (G symmetric -> B^T form exact)
    gemm_bt<u16><<<dim3(8, 2, BB), blk, 0, stream>>>(
        Wk_b, Gb, P2, nullptr, 256, 256, 256, 0, 65536, 262144);

    // stats/S/kv/Zt (short serial tail)
    skvz<<<dim3(BB * HH), blk, 0, stream>>>(P2, su, Wk_b, Wv_b, Wq_b, Zt);

    // Ft[b] = Wo Zt_b^T : [256x512]x[512x256]
    gemm_bt<u16><<<dim3(2, 2, BB), blk, 0, stream>>>(
        Wo_b, Zt, Ft, nullptr, 512, 512, 256, 0, 131072, 65536);

    // out = u_b Ft^T + bo (bf16 A via GLD, 16-wave low-acc block)
    gemm_out<<<dim3(128, 1, BB), dim3(1024), 0, stream>>>(u_b, Ft, out, bo);
}